// Round 9
// baseline (3257.677 us; speedup 1.0000x reference)
//
#include <hip/hip_runtime.h>
#include <hip/hip_bf16.h>
#include <cstdint>

typedef __attribute__((ext_vector_type(8))) short short8;
typedef __attribute__((ext_vector_type(4))) float f32x4;
typedef __attribute__((ext_vector_type(4))) short short4v;

__device__ __forceinline__ float b2f(short s) {
    unsigned u = ((unsigned)(unsigned short)s) << 16;
    return __builtin_bit_cast(float, u);
}
__device__ __forceinline__ short f2b(float f) {
    unsigned u = __builtin_bit_cast(unsigned, f);
    u += 0x7fff + ((u >> 16) & 1);   // RNE
    return (short)(u >> 16);
}

__device__ __forceinline__ float gelu_t(float x) {
    float u = 0.7978845608028654f * (x + 0.044715f * x * x * x);
    float e = __expf(2.0f * u);
    float t = 1.0f - __fdividef(2.0f, e + 1.0f);
    return 0.5f * x * (1.0f + t);
}

// Ash layout: [128 rows][512 cols] bf16, chunk-swizzled: 16B-chunk c of row r
// stored at chunk (c ^ (r&15)).
__device__ __forceinline__ int ashC(int r, int c) {            // chunk c in 0..63
    return r * 512 + (((c) ^ (r & 15)) << 3);
}

// =====================================================================
// Mega-kernel v3: block = 128 rows x one view k (blockIdx.z).
//   k==0 : encoder(x);  k>=1 : transform_k (3 layers) then encoder (3)
// Activations resident in LDS Ash[128][512] (swizzled, 128 KiB).
// Weights go global -> VGPR directly (8 fragments/wave/step, each a
// 16-line fully-consumed dwordx4; W step-slice is L1/L2-resident).
// NO Wbuf, NO per-step barriers: waves free-run within a layer;
// only 2 barriers per layer around the epilogue (cross-wave exchange).
// W-regs ping-pong (cur/nxt) so each load has ~1 compute phase of cover.
// Ends with fused LN + L2-normalize + coalesced z write.
// =====================================================================
__global__ __launch_bounds__(512, 2)
void mega_kernel(const short* __restrict__ xb,     // [CH,512] bf16
                 const short* __restrict__ wt,     // 36 mats [512][512] n-major
                 const float* __restrict__ tb1, const float* __restrict__ tb2,
                 const float* __restrict__ tb3,
                 const float* __restrict__ eb1, const float* __restrict__ eb2,
                 const float* __restrict__ eb3,
                 const float* __restrict__ lngm, const float* __restrict__ lnbt,
                 short* __restrict__ zst,          // [12,CH,512] bf16
                 int CH) {
    __shared__ alignas(16) short Ash[128 * 512];   // 131072 B

    const int tid  = threadIdx.x;
    const int lane = tid & 63;
    const int w    = tid >> 6;           // 0..7
    const int wr   = w >> 2, wc = w & 3; // 2x4 wave grid: 64 rows x 128 cols
    const int kview = blockIdx.z;
    const long row0 = (long)blockIdx.x * 128;
    const long WM   = 512L * 512L;
    const int  L    = (kview == 0) ? 3 : 6;

    const int lr = lane & 15, hi = lane >> 4;

    // ---- x tile -> Ash ----
    for (int it = 0; it < 16; ++it) {
        const int r = it * 8 + w;                  // wave-uniform row
        short8 v = *(const short8*)&xb[(row0 + r) * 512 + lane * 8];
        *(short8*)&Ash[ashC(r, lane)] = v;
    }
    __syncthreads();

    auto widx_of = [&](int l) -> long {
        const int le = (kview == 0) ? l + 3 : l;
        return (le == 0) ? (long)(kview - 1)
             : (le == 1) ? (long)(11 + kview - 1)
             : (le == 2) ? (long)(22 + kview - 1)
             : (long)(33 + (le - 3));
    };

    // per-lane W fragment base offset (shorts), frag n, before step k-offset:
    //   (wc*128 + n*16 + lr) * 512 + hi*8      (+ s*32 per step)
    f32x4 acc[4][8] = {};
    short8 cur[8], nxt[8];

    {
        const short* W0 = wt + widx_of(0) * WM;
#pragma unroll
        for (int n = 0; n < 8; ++n)
            cur[n] = *(const short8*)&W0[(long)(wc * 128 + n * 16 + lr) * 512 + hi * 8];
    }

    for (int l = 0; l < L; ++l) {
        const short* Wc = wt + widx_of(l) * WM;
        const short* Wn = (l + 1 < L) ? wt + widx_of(l + 1) * WM : Wc;

        for (int sp = 0; sp < 8; ++sp) {
            const int s0 = sp * 2, s1 = sp * 2 + 1;

            // issue loads for step s1
#pragma unroll
            for (int n = 0; n < 8; ++n)
                nxt[n] = *(const short8*)&Wc[(long)(wc * 128 + n * 16 + lr) * 512 + s1 * 32 + hi * 8];

            // compute step s0 with cur
            {
                short8 a[4];
#pragma unroll
                for (int m = 0; m < 4; ++m)
                    a[m] = *(const short8*)&Ash[ashC(wr * 64 + m * 16 + lr, s0 * 4 + hi)];
#pragma unroll
                for (int n = 0; n < 8; ++n)
#pragma unroll
                    for (int m = 0; m < 4; ++m)
                        acc[m][n] = __builtin_amdgcn_mfma_f32_16x16x32_bf16(a[m], cur[n], acc[m][n], 0, 0, 0);
            }

            // issue loads for step s0+2 (or next layer's step 0 at sp==7)
            {
                const short* Wp = (sp == 7) ? Wn : Wc;
                const int koff = (sp == 7) ? 0 : (s1 + 1) * 32;
#pragma unroll
                for (int n = 0; n < 8; ++n)
                    cur[n] = *(const short8*)&Wp[(long)(wc * 128 + n * 16 + lr) * 512 + koff + hi * 8];
            }

            // compute step s1 with nxt
            {
                short8 a[4];
#pragma unroll
                for (int m = 0; m < 4; ++m)
                    a[m] = *(const short8*)&Ash[ashC(wr * 64 + m * 16 + lr, s1 * 4 + hi)];
#pragma unroll
                for (int n = 0; n < 8; ++n)
#pragma unroll
                    for (int m = 0; m < 4; ++m)
                        acc[m][n] = __builtin_amdgcn_mfma_f32_16x16x32_bf16(a[m], nxt[n], acc[m][n], 0, 0, 0);
            }
        }

        // ---- layer epilogue: bias (+GELU), bf16, write back into Ash ----
        __syncthreads();     // all waves' layer-l Ash reads done
        {
            const int le = (kview == 0) ? l + 3 : l;
            const float* bp = (le == 0) ? tb1 + (long)(kview - 1) * 512
                            : (le == 1) ? tb2 + (long)(kview - 1) * 512
                            : (le == 2) ? tb3 + (long)(kview - 1) * 512
                            : (le == 3) ? eb1 : (le == 4) ? eb2 : eb3;
            const bool g = (le == 0) | (le == 1) | (le == 3) | (le == 4);
#pragma unroll
            for (int n = 0; n < 8; ++n) {
                const int col = wc * 128 + n * 16 + lr;
                const float bv = bp[col];
#pragma unroll
                for (int m = 0; m < 4; ++m) {
#pragma unroll
                    for (int i = 0; i < 4; ++i) {
                        const int row = wr * 64 + m * 16 + hi * 4 + i;
                        float v = acc[m][n][i] + bv;
                        if (g) v = gelu_t(v);
                        Ash[ashC(row, col >> 3) + (col & 7)] = f2b(v);
                    }
                    acc[m][n] = (f32x4){0.f, 0.f, 0.f, 0.f};
                }
            }
        }
        __syncthreads();     // epilogue visible before next layer's reads
    }

    // ---- fused LN + L2-normalize + z write: one wave per row ----
    for (int it = 0; it < 16; ++it) {
        const int row = it * 8 + w;
        short8 t = *(const short8*)&Ash[ashC(row, lane)];
        float v[8];
        float sum = 0.f, ss = 0.f;
#pragma unroll
        for (int j = 0; j < 8; ++j) { v[j] = b2f(t[j]); sum += v[j]; ss += v[j] * v[j]; }
#pragma unroll
        for (int o = 1; o < 64; o <<= 1) { sum += __shfl_xor(sum, o, 64); ss += __shfl_xor(ss, o, 64); }
        const float mu = sum * (1.f / 512.f);
        const float var = ss * (1.f / 512.f) - mu * mu;
        const float rs = rsqrtf(var + 1e-5f);
        float y[8]; float nsq = 0.f;
#pragma unroll
        for (int j = 0; j < 8; ++j) {
            const int col = lane * 8 + j;
            y[j] = (v[j] - mu) * rs * lngm[col] + lnbt[col];
            nsq += y[j] * y[j];
        }
#pragma unroll
        for (int o = 1; o < 64; o <<= 1) nsq += __shfl_xor(nsq, o, 64);
        const float inv = 1.f / fmaxf(sqrtf(nsq), 1e-8f);
        short8 o8;
#pragma unroll
        for (int j = 0; j < 8; ++j) o8[j] = f2b(y[j] * inv);
        *(short8*)&zst[((long)kview * CH + row0 + row) * 512 + lane * 8] = o8;
    }
}

// ---- transpose+convert: dst[n][k] = bf16(src[k][n]), one 512x512 per blockIdx.z ----
__global__ __launch_bounds__(256)
void transpose_conv(const float* __restrict__ src, short* __restrict__ dst) {
    __shared__ float t[32][33];
    const long moff = (long)blockIdx.z * 512 * 512;
    const float* s = src + moff;
    short* d = dst + moff;
    const int tx = threadIdx.x & 31, ty = threadIdx.x >> 5;
    const int bi = blockIdx.x, bj = blockIdx.y;
#pragma unroll
    for (int j = 0; j < 4; ++j)
        t[ty + j * 8][tx] = s[(long)(bi * 32 + ty + j * 8) * 512 + bj * 32 + tx];
    __syncthreads();
#pragma unroll
    for (int j = 0; j < 4; ++j)
        d[(long)(bj * 32 + ty + j * 8) * 512 + bi * 32 + tx] = f2b(t[tx][ty + j * 8]);
}

// ---- f32 -> bf16 elementwise ----
__global__ __launch_bounds__(256)
void conv_f32_bf16(const float* __restrict__ src, short* __restrict__ dst, long n) {
    long i = ((long)blockIdx.x * 256 + threadIdx.x) * 4;
    if (i >= n) return;
    float4 f = *(const float4*)&src[i];
    short4v o;
    o[0] = f2b(f.x); o[1] = f2b(f.y); o[2] = f2b(f.z); o[3] = f2b(f.w);
    *(short4v*)&dst[i] = o;
}

// ---- loss: 4 waves/block, one b per wave; 12x12 Gram + per-k logsumexp ----
__global__ __launch_bounds__(256)
void loss_kernel(const short* __restrict__ Z, float* __restrict__ out, int CH) {
    const int wid = threadIdx.x >> 6, lane = threadIdx.x & 63;
    const long b = (long)blockIdx.x * 4 + wid;
    __shared__ float G[4][12][12];
    float v[12][8];
#pragma unroll
    for (int sIdx = 0; sIdx < 12; ++sIdx) {
        short8 t = *(const short8*)&Z[((long)sIdx * CH + b) * 512 + lane * 8];
#pragma unroll
        for (int j = 0; j < 8; ++j) v[sIdx][j] = b2f(t[j]);
    }
#pragma unroll
    for (int i = 0; i < 12; ++i) {
#pragma unroll
        for (int j = i + 1; j < 12; ++j) {
            float p = 0.f;
#pragma unroll
            for (int t = 0; t < 8; ++t) p += v[i][t] * v[j][t];
#pragma unroll
            for (int o = 1; o < 64; o <<= 1) p += __shfl_xor(p, o, 64);
            if (lane == 0) { G[wid][i][j] = p; G[wid][j][i] = p; }
        }
    }
    __syncthreads();
    float contrib = 0.f;
    if (lane >= 1 && lane <= 11) {
        const int k = lane;
        const float pos = G[wid][0][k];
        float mx = pos;
        for (int l = 1; l <= 11; ++l) if (l != k) mx = fmaxf(mx, G[wid][l][k]);
        float sum = expf(pos - mx);
        for (int l = 1; l <= 11; ++l) if (l != k) sum += expf(G[wid][l][k] - mx);
        contrib = pos - (mx + logf(sum));
    }
#pragma unroll
    for (int o = 1; o < 64; o <<= 1) contrib += __shfl_xor(contrib, o, 64);
    if (lane == 0) out[b] = -contrib;
}

// ---------------- host ----------------
extern "C" void kernel_launch(void* const* d_in, const int* in_sizes, int n_in,
                              void* d_out, int out_size, void* d_ws, size_t ws_size,
                              hipStream_t stream) {
    const float* x    = (const float*)d_in[0];
    const float* tW1  = (const float*)d_in[1];
    const float* tb1  = (const float*)d_in[2];
    const float* tW2  = (const float*)d_in[3];
    const float* tb2  = (const float*)d_in[4];
    const float* tW3  = (const float*)d_in[5];
    const float* tb3  = (const float*)d_in[6];
    const float* eW1  = (const float*)d_in[7];
    const float* eb1  = (const float*)d_in[8];
    const float* eW2  = (const float*)d_in[9];
    const float* eb2  = (const float*)d_in[10];
    const float* eW3  = (const float*)d_in[11];
    const float* eb3  = (const float*)d_in[12];
    const float* ln_g = (const float*)d_in[13];
    const float* ln_b = (const float*)d_in[14];

    const int  B    = in_sizes[0] / 512;   // 16384
    const long WMAT = 512L * 512L;

    // ---- adaptive chunking: weights + xb + 12 z slabs (bf16) ----
    int  c  = 1;
    long CH = B;
    for (;;) {
        CH = (long)B / c;
        size_t need = (size_t)36 * WMAT * 2 + (size_t)13 * CH * 512 * 2 + 4096;
        if (need <= ws_size || CH <= 128) break;
        c <<= 1;
    }

    short* wt  = (short*)d_ws;             // 36 transposed bf16 weight mats
    short* xb  = wt + 36L * WMAT;          // [CH,512] bf16 chunk of x
    short* zst = xb + CH * 512;            // [12,CH,512] bf16 z-store

    // --- weight transpose+convert (once) ---
    {
        dim3 tgK(16, 16, 11), tg1(16, 16, 1);
        transpose_conv<<<tgK, 256, 0, stream>>>(tW1, wt + 0L * WMAT);
        transpose_conv<<<tgK, 256, 0, stream>>>(tW2, wt + 11L * WMAT);
        transpose_conv<<<tgK, 256, 0, stream>>>(tW3, wt + 22L * WMAT);
        transpose_conv<<<tg1, 256, 0, stream>>>(eW1, wt + 33L * WMAT);
        transpose_conv<<<tg1, 256, 0, stream>>>(eW2, wt + 34L * WMAT);
        transpose_conv<<<tg1, 256, 0, stream>>>(eW3, wt + 35L * WMAT);
    }

    const long SC = CH * 512;
    const dim3 gM((unsigned)(CH / 128), 1, 12);

    for (int ch = 0; ch < c; ++ch) {
        conv_f32_bf16<<<(unsigned)((SC / 4 + 255) / 256), 256, 0, stream>>>(
            x + (long)ch * SC, xb, SC);

        mega_kernel<<<gM, 512, 0, stream>>>(xb, wt, tb1, tb2, tb3, eb1, eb2, eb3,
                                            ln_g, ln_b, zst, (int)CH);

        loss_kernel<<<(unsigned)(CH / 4), 256, 0, stream>>>(
            zst, (float*)d_out + (long)ch * CH, (int)CH);
    }
}

// Round 10
// 1614.862 us; speedup vs baseline: 2.0173x; 2.0173x over previous
//
#include <hip/hip_runtime.h>
#include <hip/hip_bf16.h>
#include <cstdint>

typedef __attribute__((ext_vector_type(8))) short short8;
typedef __attribute__((ext_vector_type(4))) float f32x4;
typedef __attribute__((ext_vector_type(4))) short short4v;

__device__ __forceinline__ float b2f(short s) {
    unsigned u = ((unsigned)(unsigned short)s) << 16;
    return __builtin_bit_cast(float, u);
}
__device__ __forceinline__ short f2b(float f) {
    unsigned u = __builtin_bit_cast(unsigned, f);
    u += 0x7fff + ((u >> 16) & 1);   // RNE
    return (short)(u >> 16);
}

__device__ __forceinline__ float gelu_t(float x) {
    // tanh-form GELU; |err vs erf-form| < ~3e-3 absolute
    float u = 0.7978845608028654f * (x + 0.044715f * x * x * x);
    float e = __expf(2.0f * u);
    float t = 1.0f - __fdividef(2.0f, e + 1.0f);
    return 0.5f * x * (1.0f + t);
}

__device__ __forceinline__ void async16(const void* g, void* l) {
    __builtin_amdgcn_global_load_lds(
        (const __attribute__((address_space(1))) unsigned int*)g,
        (__attribute__((address_space(3))) unsigned int*)l, 16, 0, 0);
}

// ---- GEMM: C[M,512] = A[M,512] @ Bt[512,512]^T + bias, opt GELU; batched over blockIdx.z ----
// T3-minimum pipeline: double-buffered LDS staging, stage(t+1) issued BEFORE
// compute(t), single __syncthreads per K-step (vmcnt drain lands after compute).
#define BM 128
#define BN 128
#define BKK 64

template<bool GELU>
__global__ __launch_bounds__(256)
void gemm_bt(const short* __restrict__ A, long sA,
             const short* __restrict__ Bt, long sB,
             const float* __restrict__ bias, long sBias,
             short* __restrict__ C, long sC) {
    const int z = blockIdx.z;
    A    += (long)z * sA;
    Bt   += (long)z * sB;
    bias += (long)z * sBias;
    C    += (long)z * sC;

    // smem: 2 buffers x (As 8192 + Bs 8192 shorts) = 65536 B.
    // Epilogue reuses the same memory (4 waves x 64x72-short tiles = 36864 B).
    __shared__ alignas(16) short smem[2 * 2 * BM * BKK];

    const int tid  = threadIdx.x;
    const int lane = tid & 63;
    const int w    = tid >> 6;
    const int wr   = w >> 1, wc = w & 1;
    const long arow0 = (long)blockIdx.x * BM;
    const long brow0 = (long)blockIdx.y * BN;
    const int  K = 512;

    f32x4 acc[4][4] = {};

    const int srow = lane >> 3;                    // 0..7 (row&7 of staged row)
    const int scol = ((lane & 7) ^ srow) * 8;      // pre-swizzled global chunk

    // stage K-step at k0 into buffer b
    auto stage = [&](int b, int k0) {
        short* As = smem + b * (2 * BM * BKK);
        short* Bs = As + BM * BKK;
#pragma unroll
        for (int i = 0; i < 4; ++i) {
            const int r0 = (i * 4 + w) * 8;        // wave-uniform row group
            async16(A  + (arow0 + r0 + srow) * K + k0 + scol, &As[r0 * BKK]);
            async16(Bt + (brow0 + r0 + srow) * K + k0 + scol, &Bs[r0 * BKK]);
        }
    };

    stage(0, 0);
    __syncthreads();                               // buf0 ready

    int buf = 0;
    for (int k0 = 0; k0 < K; k0 += BKK) {
        if (k0 + BKK < K) stage(buf ^ 1, k0 + BKK);   // issue early: overlaps compute
        const short* As = smem + buf * (2 * BM * BKK);
        const short* Bs = As + BM * BKK;
        const int lr = lane & 15;
        const int r7 = lane & 7;
#pragma unroll
        for (int kk = 0; kk < BKK; kk += 32) {
            const int c0 = (kk >> 3) + (lane >> 4);   // 16B-chunk index pre-swizzle
            short8 a[4], b[4];
#pragma unroll
            for (int m = 0; m < 4; ++m)
                a[m] = *(const short8*)&As[(wr * 64 + m * 16 + lr) * BKK + ((c0 ^ r7) * 8)];
#pragma unroll
            for (int n = 0; n < 4; ++n)
                b[n] = *(const short8*)&Bs[(wc * 64 + n * 16 + lr) * BKK + ((c0 ^ r7) * 8)];
#pragma unroll
            for (int m = 0; m < 4; ++m)
#pragma unroll
                for (int n = 0; n < 4; ++n)
                    acc[m][n] = __builtin_amdgcn_mfma_f32_16x16x32_bf16(
                        a[m], b[n], acc[m][n], 0, 0, 0);
        }
        __syncthreads();   // drains vmcnt: stage(k0+64) complete; all reads of buf done
        buf ^= 1;
    }

    // ---- epilogue: acc -> (bias, GELU, bf16) -> wave-private LDS -> 16B stores ----
    short* E = smem + w * (64 * 72);               // [64 rows][72 cols], wave-private
    const int cl = lane & 15;
    const int rl = (lane >> 4) * 4;
#pragma unroll
    for (int n = 0; n < 4; ++n) {
        const int col = (int)brow0 + wc * 64 + n * 16 + cl;
        const float bs = bias[col];
#pragma unroll
        for (int m = 0; m < 4; ++m) {
#pragma unroll
            for (int i = 0; i < 4; ++i) {
                float cv = acc[m][n][i] + bs;
                if (GELU) cv = gelu_t(cv);
                E[(m * 16 + rl + i) * 72 + n * 16 + cl] = f2b(cv);
            }
        }
    }
    // wave-private region: lgkmcnt orders within wave, no barrier needed
#pragma unroll
    for (int chunk = 0; chunk < 8; ++chunk) {
        const int rloc = chunk * 8 + (lane >> 3);
        const int c0   = (lane & 7) * 8;
        short8 v = *(const short8*)&E[rloc * 72 + c0];
        *(short8*)&C[(arow0 + wr * 64 + rloc) * 512 + brow0 + wc * 64 + c0] = v;
    }
}

// ---- transpose+convert: dst[n][k] = bf16(src[k][n]), one 512x512 per blockIdx.z ----
__global__ __launch_bounds__(256)
void transpose_conv(const float* __restrict__ src, short* __restrict__ dst) {
    __shared__ float t[32][33];
    const long moff = (long)blockIdx.z * 512 * 512;
    const float* s = src + moff;
    short* d = dst + moff;
    const int tx = threadIdx.x & 31, ty = threadIdx.x >> 5;
    const int bi = blockIdx.x, bj = blockIdx.y;
#pragma unroll
    for (int j = 0; j < 4; ++j)
        t[ty + j * 8][tx] = s[(long)(bi * 32 + ty + j * 8) * 512 + bj * 32 + tx];
    __syncthreads();
#pragma unroll
    for (int j = 0; j < 4; ++j)
        d[(long)(bj * 32 + ty + j * 8) * 512 + bi * 32 + tx] = f2b(t[tx][ty + j * 8]);
}

// ---- f32 -> bf16 elementwise ----
__global__ __launch_bounds__(256)
void conv_f32_bf16(const float* __restrict__ src, short* __restrict__ dst, long n) {
    long i = ((long)blockIdx.x * 256 + threadIdx.x) * 4;
    if (i >= n) return;
    float4 f = *(const float4*)&src[i];
    short4v o;
    o[0] = f2b(f.x); o[1] = f2b(f.y); o[2] = f2b(f.z); o[3] = f2b(f.w);
    *(short4v*)&dst[i] = o;
}

// ---- LayerNorm + L2 normalize: one wave per 512-row ----
__global__ __launch_bounds__(256)
void ln_normalize(const short* __restrict__ in, const float* __restrict__ g,
                  const float* __restrict__ bta, short* __restrict__ outz, long nrows) {
    const int wid = threadIdx.x >> 6, lane = threadIdx.x & 63;
    const long row = (long)blockIdx.x * 4 + wid;
    if (row >= nrows) return;
    short8 t = *(const short8*)&in[row * 512 + lane * 8];
    float v[8];
    float s = 0.f, ss = 0.f;
#pragma unroll
    for (int j = 0; j < 8; ++j) { v[j] = b2f(t[j]); s += v[j]; ss += v[j] * v[j]; }
#pragma unroll
    for (int o = 1; o < 64; o <<= 1) { s += __shfl_xor(s, o, 64); ss += __shfl_xor(ss, o, 64); }
    const float mu = s * (1.f / 512.f);
    const float var = ss * (1.f / 512.f) - mu * mu;
    const float rs = rsqrtf(var + 1e-5f);
    float y[8]; float nsq = 0.f;
#pragma unroll
    for (int j = 0; j < 8; ++j) {
        const int col = lane * 8 + j;
        y[j] = (v[j] - mu) * rs * g[col] + bta[col];
        nsq += y[j] * y[j];
    }
#pragma unroll
    for (int o = 1; o < 64; o <<= 1) nsq += __shfl_xor(nsq, o, 64);
    const float inv = 1.f / fmaxf(sqrtf(nsq), 1e-8f);
    short8 o8;
#pragma unroll
    for (int j = 0; j < 8; ++j) o8[j] = f2b(y[j] * inv);
    *(short8*)&outz[row * 512 + lane * 8] = o8;
}

// ---- loss: 4 waves/block, one b per wave; 12x12 Gram + per-k logsumexp ----
__global__ __launch_bounds__(256)
void loss_kernel(const short* __restrict__ Z, float* __restrict__ out, int CH) {
    const int wid = threadIdx.x >> 6, lane = threadIdx.x & 63;
    const long b = (long)blockIdx.x * 4 + wid;
    __shared__ float G[4][12][12];
    float v[12][8];
#pragma unroll
    for (int sIdx = 0; sIdx < 12; ++sIdx) {
        short8 t = *(const short8*)&Z[((long)sIdx * CH + b) * 512 + lane * 8];
#pragma unroll
        for (int j = 0; j < 8; ++j) v[sIdx][j] = b2f(t[j]);
    }
#pragma unroll
    for (int i = 0; i < 12; ++i) {
#pragma unroll
        for (int j = i + 1; j < 12; ++j) {
            float p = 0.f;
#pragma unroll
            for (int t = 0; t < 8; ++t) p += v[i][t] * v[j][t];
#pragma unroll
            for (int o = 1; o < 64; o <<= 1) p += __shfl_xor(p, o, 64);
            if (lane == 0) { G[wid][i][j] = p; G[wid][j][i] = p; }
        }
    }
    __syncthreads();
    float contrib = 0.f;
    if (lane >= 1 && lane <= 11) {
        const int k = lane;
        const float pos = G[wid][0][k];
        float mx = pos;
        for (int l = 1; l <= 11; ++l) if (l != k) mx = fmaxf(mx, G[wid][l][k]);
        float sum = expf(pos - mx);
        for (int l = 1; l <= 11; ++l) if (l != k) sum += expf(G[wid][l][k] - mx);
        contrib = pos - (mx + logf(sum));
    }
#pragma unroll
    for (int o = 1; o < 64; o <<= 1) contrib += __shfl_xor(contrib, o, 64);
    if (lane == 0) out[b] = -contrib;
}

// ---------------- host ----------------
extern "C" void kernel_launch(void* const* d_in, const int* in_sizes, int n_in,
                              void* d_out, int out_size, void* d_ws, size_t ws_size,
                              hipStream_t stream) {
    const float* x    = (const float*)d_in[0];
    const float* tW1  = (const float*)d_in[1];
    const float* tb1  = (const float*)d_in[2];
    const float* tW2  = (const float*)d_in[3];
    const float* tb2  = (const float*)d_in[4];
    const float* tW3  = (const float*)d_in[5];
    const float* tb3  = (const float*)d_in[6];
    const float* eW1  = (const float*)d_in[7];
    const float* eb1  = (const float*)d_in[8];
    const float* eW2  = (const float*)d_in[9];
    const float* eb2  = (const float*)d_in[10];
    const float* eW3  = (const float*)d_in[11];
    const float* eb3  = (const float*)d_in[12];
    const float* ln_g = (const float*)d_in[13];
    const float* ln_b = (const float*)d_in[14];

    const int  B    = in_sizes[0] / 512;   // 16384
    const long WMAT = 512L * 512L;

    // ---- adaptive chunking: footprint = weights + 3 slabs of 12*CH*512 bf16 ----
    int  c  = 1;
    long CH = B;
    for (;;) {
        CH = (long)B / c;
        size_t need = (size_t)36 * WMAT * 2 + (size_t)36 * CH * 512 * 2 + 4096;
        if (need <= ws_size || CH <= 256) break;
        c <<= 1;
    }
    const long SLAB = 12L * CH * 512;      // elements per 12-view slab

    short* wt  = (short*)d_ws;             // 36 transposed bf16 weight mats
    short* X12 = wt  + 36L * WMAT;         // [12, CH, 512]: slot0 = x, 1..11 = t_k(x); reused as z-store
    short* hA  = X12 + SLAB;               // [12, CH, 512] scratch
    short* hB  = hA  + SLAB;               // [12, CH, 512] scratch

    // --- weight transpose+convert (once) ---
    {
        dim3 tgK(16, 16, 11), tg1(16, 16, 1);
        transpose_conv<<<tgK, 256, 0, stream>>>(tW1, wt + 0L * WMAT);
        transpose_conv<<<tgK, 256, 0, stream>>>(tW2, wt + 11L * WMAT);
        transpose_conv<<<tgK, 256, 0, stream>>>(tW3, wt + 22L * WMAT);
        transpose_conv<<<tg1, 256, 0, stream>>>(eW1, wt + 33L * WMAT);
        transpose_conv<<<tg1, 256, 0, stream>>>(eW2, wt + 34L * WMAT);
        transpose_conv<<<tg1, 256, 0, stream>>>(eW3, wt + 35L * WMAT);
    }

    const long SC = CH * 512;              // one [CH,512] slab
    const dim3 gT((unsigned)(CH / BM), 512 / BN, 11);        // batched transforms
    const dim3 gE((unsigned)(12 * CH / BM), 512 / BN, 1);    // encoder over all 12 views
    const dim3 lng((unsigned)((12 * CH) / 4));

    for (int ch = 0; ch < c; ++ch) {
        // x chunk -> bf16 into X12 slot 0
        conv_f32_bf16<<<(unsigned)((SC / 4 + 255) / 256), 256, 0, stream>>>(
            x + (long)ch * SC, X12, SC);

        // 11 learned transforms, batched over z
        gemm_bt<true ><<<gT, 256, 0, stream>>>(X12, 0,  wt + 0L * WMAT,  WMAT, tb1, 512, hA, SC);
        gemm_bt<true ><<<gT, 256, 0, stream>>>(hA,  SC, wt + 11L * WMAT, WMAT, tb2, 512, hB, SC);
        gemm_bt<false><<<gT, 256, 0, stream>>>(hB,  SC, wt + 22L * WMAT, WMAT, tb3, 512, X12 + SC, SC);

        // shared encoder over all 12 views at once (M = 12*CH)
        gemm_bt<true ><<<gE, 256, 0, stream>>>(X12, 0, wt + 33L * WMAT, 0, eb1, 0, hA, 0);
        gemm_bt<true ><<<gE, 256, 0, stream>>>(hA,  0, wt + 34L * WMAT, 0, eb2, 0, hB, 0);
        gemm_bt<false><<<gE, 256, 0, stream>>>(hB,  0, wt + 35L * WMAT, 0, eb3, 0, hA, 0);

        // LN + L2-normalize all 12*CH rows; write z back into X12
        ln_normalize<<<lng, 256, 0, stream>>>(hA, ln_g, ln_b, X12, 12L * CH);

        // per-sample 12x12 Gram + logsumexp loss
        loss_kernel<<<(unsigned)(CH / 4), 256, 0, stream>>>(X12, (float*)d_out + (long)ch * CH, (int)CH);
    }
}

// Round 11
// 1282.944 us; speedup vs baseline: 2.5392x; 1.2587x over previous
//
#include <hip/hip_runtime.h>
#include <hip/hip_bf16.h>
#include <cstdint>

typedef __attribute__((ext_vector_type(8))) short short8;
typedef __attribute__((ext_vector_type(4))) float f32x4;
typedef __attribute__((ext_vector_type(4))) short short4v;

__device__ __forceinline__ float b2f(short s) {
    unsigned u = ((unsigned)(unsigned short)s) << 16;
    return __builtin_bit_cast(float, u);
}
__device__ __forceinline__ short f2b(float f) {
    unsigned u = __builtin_bit_cast(unsigned, f);
    u += 0x7fff + ((u >> 16) & 1);   // RNE
    return (short)(u >> 16);
}

// tanh-form GELU, 8-VALU restructure: gelu = x - x/(1+exp2(x*(c1 + c2*x^2)))
// (exact same math as 0.5x(1+tanh(...)), c's fold the 2*log2(e) factor)
__device__ __forceinline__ float gelu_t(float x) {
    const float c1 = 2.302184829f;     // 2*log2(e)*0.7978845608
    const float c2 = 0.102947246f;     // c1 * 0.044715
    float x2 = x * x;
    float t  = __builtin_fmaf(c2, x2, c1);
    float e  = __builtin_amdgcn_exp2f(x * t);
    return x - __fdividef(x, e + 1.0f);
}

__device__ __forceinline__ void async16(const void* g, void* l) {
    __builtin_amdgcn_global_load_lds(
        (const __attribute__((address_space(1))) unsigned int*)g,
        (__attribute__((address_space(3))) unsigned int*)l, 16, 0, 0);
}

// ---- GEMM: C[M,512] = A[M,512] @ Bt[512,512]^T + bias, opt GELU; batched over blockIdx.z ----
// r4-proven single-buffer 2-barrier K-loop; 1D grid with bijective XCD swizzle
// (4 consecutive swizzled blocks share an A panel on the same XCD L2).
#define BM 128
#define BN 128
#define BKK 64

template<bool GELU>
__global__ __launch_bounds__(256)
void gemm_bt(const short* __restrict__ A, long sA,
             const short* __restrict__ Bt, long sB,
             const float* __restrict__ bias, long sBias,
             short* __restrict__ C, long sC) {
    const int z = blockIdx.z;
    A    += (long)z * sA;
    Bt   += (long)z * sB;
    bias += (long)z * sBias;
    C    += (long)z * sC;

    // XCD-aware bijective swizzle: nwg = gridDim.x, always a multiple of 8 here.
    const int nwg = (int)gridDim.x;
    const int q   = nwg >> 3;
    const int bx  = (int)blockIdx.x;
    const int flat = (bx & 7) * q + (bx >> 3);
    const long arow0 = (long)(flat >> 2) * BM;   // M-tile
    const long brow0 = (long)(flat & 3) * BN;    // N-tile (4 tiles over N=512)

    // K-loop uses 16384 shorts; epilogue reuses as 4 x [64][72] wave tiles.
    __shared__ alignas(16) short smem[4 * 64 * 72];
    short* As = smem;
    short* Bs = smem + BM * BKK;

    const int tid  = threadIdx.x;
    const int lane = tid & 63;
    const int w    = tid >> 6;
    const int wr   = w >> 1, wc = w & 1;
    const int  K = 512;

    f32x4 acc[4][4] = {};

    const int srow = lane >> 3;                    // 0..7 (row&7 of staged row)
    const int scol = ((lane & 7) ^ srow) * 8;      // pre-swizzled global chunk

    for (int k0 = 0; k0 < K; k0 += BKK) {
        __syncthreads();
#pragma unroll
        for (int i = 0; i < 4; ++i) {
            const int r0 = (i * 4 + w) * 8;        // wave-uniform row group
            async16(A  + (arow0 + r0 + srow) * K + k0 + scol, &As[r0 * BKK]);
            async16(Bt + (brow0 + r0 + srow) * K + k0 + scol, &Bs[r0 * BKK]);
        }
        __syncthreads();
        const int lr = lane & 15;
        const int r7 = lane & 7;
#pragma unroll
        for (int kk = 0; kk < BKK; kk += 32) {
            const int c0 = (kk >> 3) + (lane >> 4); // 16B-chunk index pre-swizzle
            short8 a[4], b[4];
#pragma unroll
            for (int m = 0; m < 4; ++m)
                a[m] = *(const short8*)&As[(wr * 64 + m * 16 + lr) * BKK + ((c0 ^ r7) * 8)];
#pragma unroll
            for (int n = 0; n < 4; ++n)
                b[n] = *(const short8*)&Bs[(wc * 64 + n * 16 + lr) * BKK + ((c0 ^ r7) * 8)];
#pragma unroll
            for (int m = 0; m < 4; ++m)
#pragma unroll
                for (int n = 0; n < 4; ++n)
                    acc[m][n] = __builtin_amdgcn_mfma_f32_16x16x32_bf16(
                        a[m], b[n], acc[m][n], 0, 0, 0);
        }
    }

    // ---- epilogue: acc -> (bias, GELU, cvt_pk bf16) -> wave LDS tile -> 16B stores ----
    __syncthreads();                               // all ds_reads of As/Bs done
    short* E = smem + w * (64 * 72);               // [64 rows][72 cols], wave-private
    const int cl = lane & 15;
    const int rl = (lane >> 4) * 4;
#pragma unroll
    for (int n = 0; n < 4; ++n) {
        const int col = (int)brow0 + wc * 64 + n * 16 + cl;
        const float bs = bias[col];
        const int ecol = n * 16 + cl;
#pragma unroll
        for (int m = 0; m < 4; ++m) {
            float g0 = acc[m][n][0] + bs, g1 = acc[m][n][1] + bs;
            float g2 = acc[m][n][2] + bs, g3 = acc[m][n][3] + bs;
            if (GELU) { g0 = gelu_t(g0); g1 = gelu_t(g1); g2 = gelu_t(g2); g3 = gelu_t(g3); }
            unsigned p01, p23;
            asm("v_cvt_pk_bf16_f32 %0, %1, %2" : "=v"(p01) : "v"(g0), "v"(g1));
            asm("v_cvt_pk_bf16_f32 %0, %1, %2" : "=v"(p23) : "v"(g2), "v"(g3));
            const int r0 = m * 16 + rl;
            E[(r0 + 0) * 72 + ecol] = (short)(p01 & 0xffff);
            E[(r0 + 1) * 72 + ecol] = (short)(p01 >> 16);
            E[(r0 + 2) * 72 + ecol] = (short)(p23 & 0xffff);
            E[(r0 + 3) * 72 + ecol] = (short)(p23 >> 16);
        }
    }
    // wave-private region: lgkmcnt orders within wave, no barrier needed
#pragma unroll
    for (int chunk = 0; chunk < 8; ++chunk) {
        const int rloc = chunk * 8 + (lane >> 3);
        const int c0   = (lane & 7) * 8;
        short8 v = *(const short8*)&E[rloc * 72 + c0];
        *(short8*)&C[(arow0 + wr * 64 + rloc) * 512 + brow0 + wc * 64 + c0] = v;
    }
}

// ---- transpose+convert: dst[n][k] = bf16(src[k][n]), one 512x512 per blockIdx.z ----
__global__ __launch_bounds__(256)
void transpose_conv(const float* __restrict__ src, short* __restrict__ dst) {
    __shared__ float t[32][33];
    const long moff = (long)blockIdx.z * 512 * 512;
    const float* s = src + moff;
    short* d = dst + moff;
    const int tx = threadIdx.x & 31, ty = threadIdx.x >> 5;
    const int bi = blockIdx.x, bj = blockIdx.y;
#pragma unroll
    for (int j = 0; j < 4; ++j)
        t[ty + j * 8][tx] = s[(long)(bi * 32 + ty + j * 8) * 512 + bj * 32 + tx];
    __syncthreads();
#pragma unroll
    for (int j = 0; j < 4; ++j)
        d[(long)(bj * 32 + ty + j * 8) * 512 + bi * 32 + tx] = f2b(t[tx][ty + j * 8]);
}

// ---- f32 -> bf16 elementwise ----
__global__ __launch_bounds__(256)
void conv_f32_bf16(const float* __restrict__ src, short* __restrict__ dst, long n) {
    long i = ((long)blockIdx.x * 256 + threadIdx.x) * 4;
    if (i >= n) return;
    float4 f = *(const float4*)&src[i];
    short4v o;
    o[0] = f2b(f.x); o[1] = f2b(f.y); o[2] = f2b(f.z); o[3] = f2b(f.w);
    *(short4v*)&dst[i] = o;
}

// ---- fused LN + L2-normalize + 12x12 Gram + logsumexp loss ----
// One wave per sample b; z stays in f32 registers (never materialized).
// H: [12*CH, 512] bf16, view s of sample b at row s*CH + b.
__global__ __launch_bounds__(256)
void ln_loss(const short* __restrict__ H, const float* __restrict__ g,
             const float* __restrict__ bta, float* __restrict__ out, int CH) {
    const int wid = threadIdx.x >> 6, lane = threadIdx.x & 63;
    const long b = (long)blockIdx.x * 4 + wid;

    float y[12][8];
#pragma unroll
    for (int s = 0; s < 12; ++s) {
        const long row = (long)s * CH + b;
        short8 t = *(const short8*)&H[row * 512 + lane * 8];
        float v[8];
        float sum = 0.f, ss = 0.f;
#pragma unroll
        for (int j = 0; j < 8; ++j) { v[j] = b2f(t[j]); sum += v[j]; ss += v[j] * v[j]; }
#pragma unroll
        for (int o = 1; o < 64; o <<= 1) { sum += __shfl_xor(sum, o, 64); ss += __shfl_xor(ss, o, 64); }
        const float mu = sum * (1.f / 512.f);
        const float rs = rsqrtf(ss * (1.f / 512.f) - mu * mu + 1e-5f);
        float nsq = 0.f;
#pragma unroll
        for (int j = 0; j < 8; ++j) {
            const int col = lane * 8 + j;
            y[s][j] = (v[j] - mu) * rs * g[col] + bta[col];
            nsq += y[s][j] * y[s][j];
        }
#pragma unroll
        for (int o = 1; o < 64; o <<= 1) nsq += __shfl_xor(nsq, o, 64);
        const float inv = 1.f / fmaxf(sqrtf(nsq), 1e-8f);
#pragma unroll
        for (int j = 0; j < 8; ++j) y[s][j] *= inv;
    }

    __shared__ float G[4][12][12];
#pragma unroll
    for (int i = 0; i < 12; ++i) {
#pragma unroll
        for (int j = i + 1; j < 12; ++j) {
            float p = 0.f;
#pragma unroll
            for (int t = 0; t < 8; ++t) p += y[i][t] * y[j][t];
#pragma unroll
            for (int o = 1; o < 64; o <<= 1) p += __shfl_xor(p, o, 64);
            if (lane == 0) { G[wid][i][j] = p; G[wid][j][i] = p; }
        }
    }
    __syncthreads();
    float contrib = 0.f;
    if (lane >= 1 && lane <= 11) {
        const int k = lane;
        const float pos = G[wid][0][k];
        float mx = pos;
        for (int l = 1; l <= 11; ++l) if (l != k) mx = fmaxf(mx, G[wid][l][k]);
        float sum = expf(pos - mx);
        for (int l = 1; l <= 11; ++l) if (l != k) sum += expf(G[wid][l][k] - mx);
        contrib = pos - (mx + logf(sum));
    }
#pragma unroll
    for (int o = 1; o < 64; o <<= 1) contrib += __shfl_xor(contrib, o, 64);
    if (lane == 0) out[b] = -contrib;
}

// ---------------- host ----------------
extern "C" void kernel_launch(void* const* d_in, const int* in_sizes, int n_in,
                              void* d_out, int out_size, void* d_ws, size_t ws_size,
                              hipStream_t stream) {
    const float* x    = (const float*)d_in[0];
    const float* tW1  = (const float*)d_in[1];
    const float* tb1  = (const float*)d_in[2];
    const float* tW2  = (const float*)d_in[3];
    const float* tb2  = (const float*)d_in[4];
    const float* tW3  = (const float*)d_in[5];
    const float* tb3  = (const float*)d_in[6];
    const float* eW1  = (const float*)d_in[7];
    const float* eb1  = (const float*)d_in[8];
    const float* eW2  = (const float*)d_in[9];
    const float* eb2  = (const float*)d_in[10];
    const float* eW3  = (const float*)d_in[11];
    const float* eb3  = (const float*)d_in[12];
    const float* ln_g = (const float*)d_in[13];
    const float* ln_b = (const float*)d_in[14];

    const int  B    = in_sizes[0] / 512;   // 16384
    const long WMAT = 512L * 512L;

    // ---- adaptive chunking: footprint = weights + 3 slabs of 12*CH*512 bf16 ----
    int  c  = 1;
    long CH = B;
    for (;;) {
        CH = (long)B / c;
        size_t need = (size_t)36 * WMAT * 2 + (size_t)36 * CH * 512 * 2 + 4096;
        if (need <= ws_size || CH <= 256) break;
        c <<= 1;
    }
    const long SLAB = 12L * CH * 512;      // elements per 12-view slab

    short* wt  = (short*)d_ws;             // 36 transposed bf16 weight mats
    short* X12 = wt  + 36L * WMAT;         // [12, CH, 512]: slot0 = x, 1..11 = t_k(x)
    short* hA  = X12 + SLAB;               // [12, CH, 512] scratch
    short* hB  = hA  + SLAB;               // [12, CH, 512] scratch

    // --- weight transpose+convert (once) ---
    {
        dim3 tgK(16, 16, 11), tg1(16, 16, 1);
        transpose_conv<<<tgK, 256, 0, stream>>>(tW1, wt + 0L * WMAT);
        transpose_conv<<<tgK, 256, 0, stream>>>(tW2, wt + 11L * WMAT);
        transpose_conv<<<tgK, 256, 0, stream>>>(tW3, wt + 22L * WMAT);
        transpose_conv<<<tg1, 256, 0, stream>>>(eW1, wt + 33L * WMAT);
        transpose_conv<<<tg1, 256, 0, stream>>>(eW2, wt + 34L * WMAT);
        transpose_conv<<<tg1, 256, 0, stream>>>(eW3, wt + 35L * WMAT);
    }

    const long SC = CH * 512;              // one [CH,512] slab
    // 1D swizzled grids: nwg = Mtiles*4 (always a multiple of 8 for CH >= 256)
    const dim3 gT((unsigned)(CH / 32), 1, 11);        // transforms: M = CH
    const dim3 gE((unsigned)(3 * CH / 8), 1, 1);      // encoder: M = 12*CH

    for (int ch = 0; ch < c; ++ch) {
        // x chunk -> bf16 into X12 slot 0
        conv_f32_bf16<<<(unsigned)((SC / 4 + 255) / 256), 256, 0, stream>>>(
            x + (long)ch * SC, X12, SC);

        // 11 learned transforms, batched over z
        gemm_bt<true ><<<gT, 256, 0, stream>>>(X12, 0,  wt + 0L * WMAT,  WMAT, tb1, 512, hA, SC);
        gemm_bt<true ><<<gT, 256, 0, stream>>>(hA,  SC, wt + 11L * WMAT, WMAT, tb2, 512, hB, SC);
        gemm_bt<false><<<gT, 256, 0, stream>>>(hB,  SC, wt + 22L * WMAT, WMAT, tb3, 512, X12 + SC, SC);

        // shared encoder over all 12 views at once (M = 12*CH)
        gemm_bt<true ><<<gE, 256, 0, stream>>>(X12, 0, wt + 33L * WMAT, 0, eb1, 0, hA, 0);
        gemm_bt<true ><<<gE, 256, 0, stream>>>(hA,  0, wt + 34L * WMAT, 0, eb2, 0, hB, 0);
        gemm_bt<false><<<gE, 256, 0, stream>>>(hB,  0, wt + 35L * WMAT, 0, eb3, 0, hA, 0);

        // fused LN + L2-normalize + Gram + loss (z stays in registers)
        ln_loss<<<(unsigned)(CH / 4), 256, 0, stream>>>(
            hA, ln_g, ln_b, (float*)d_out + (long)ch * CH, (int)CH);
    }
}

// Round 12
// 1131.360 us; speedup vs baseline: 2.8794x; 1.1340x over previous
//
#include <hip/hip_runtime.h>
#include <hip/hip_bf16.h>
#include <cstdint>

typedef __attribute__((ext_vector_type(8))) short short8;
typedef __attribute__((ext_vector_type(4))) float f32x4;
typedef __attribute__((ext_vector_type(4))) short short4v;

__device__ __forceinline__ float b2f(short s) {
    unsigned u = ((unsigned)(unsigned short)s) << 16;
    return __builtin_bit_cast(float, u);
}
__device__ __forceinline__ short f2b(float f) {
    unsigned u = __builtin_bit_cast(unsigned, f);
    u += 0x7fff + ((u >> 16) & 1);   // RNE
    return (short)(u >> 16);
}

// tanh-form GELU, 8-VALU: gelu = x - x/(1+exp2(x*(c1 + c2*x^2)))
__device__ __forceinline__ float gelu_t(float x) {
    const float c1 = 2.302184829f;     // 2*log2(e)*0.7978845608
    const float c2 = 0.102947246f;     // c1 * 0.044715
    float x2 = x * x;
    float t  = __builtin_fmaf(c2, x2, c1);
    float e  = __builtin_amdgcn_exp2f(x * t);
    return x - __fdividef(x, e + 1.0f);
}

__device__ __forceinline__ void async16(const void* g, void* l) {
    __builtin_amdgcn_global_load_lds(
        (const __attribute__((address_space(1))) unsigned int*)g,
        (__attribute__((address_space(3))) unsigned int*)l, 16, 0, 0);
}

// ---- GEMM: C[M,512] = A[M,512] @ Bt[512,512]^T + bias, opt GELU; batched over blockIdx.z ----
#define BM 128
#define BN 128
#define BKK 64

template<bool GELU>
__global__ __launch_bounds__(256)
void gemm_bt(const short* __restrict__ A, long sA,
             const short* __restrict__ Bt, long sB,
             const float* __restrict__ bias, long sBias,
             short* __restrict__ C, long sC) {
    const int z = blockIdx.z;
    A    += (long)z * sA;
    Bt   += (long)z * sB;
    bias += (long)z * sBias;
    C    += (long)z * sC;

    // XCD-aware bijective swizzle (nwg always a multiple of 8 here).
    const int nwg = (int)gridDim.x;
    const int q   = nwg >> 3;
    const int bx  = (int)blockIdx.x;
    const int flat = (bx & 7) * q + (bx >> 3);
    const long arow0 = (long)(flat >> 2) * BM;   // M-tile
    const long brow0 = (long)(flat & 3) * BN;    // N-tile (4 over N=512)

    // K-loop: As+Bs = 16384 shorts (32 KB). Epilogue reuses as 4 x [32][72].
    __shared__ alignas(16) short smem[2 * BM * BKK];
    short* As = smem;
    short* Bs = smem + BM * BKK;

    const int tid  = threadIdx.x;
    const int lane = tid & 63;
    const int w    = tid >> 6;
    const int wr   = w >> 1, wc = w & 1;
    const int  K = 512;

    f32x4 acc[4][4] = {};

    const int srow = lane >> 3;                    // 0..7 (row&7 of staged row)
    const int scol = ((lane & 7) ^ srow) * 8;      // pre-swizzled global chunk

    for (int k0 = 0; k0 < K; k0 += BKK) {
        __syncthreads();
#pragma unroll
        for (int i = 0; i < 4; ++i) {
            const int r0 = (i * 4 + w) * 8;        // wave-uniform row group
            async16(A  + (arow0 + r0 + srow) * K + k0 + scol, &As[r0 * BKK]);
            async16(Bt + (brow0 + r0 + srow) * K + k0 + scol, &Bs[r0 * BKK]);
        }
        __syncthreads();
        const int lr = lane & 15;
        const int r7 = lane & 7;
#pragma unroll
        for (int kk = 0; kk < BKK; kk += 32) {
            const int c0 = (kk >> 3) + (lane >> 4); // 16B-chunk index pre-swizzle
            short8 a[4], b[4];
#pragma unroll
            for (int m = 0; m < 4; ++m)
                a[m] = *(const short8*)&As[(wr * 64 + m * 16 + lr) * BKK + ((c0 ^ r7) * 8)];
#pragma unroll
            for (int n = 0; n < 4; ++n)
                b[n] = *(const short8*)&Bs[(wc * 64 + n * 16 + lr) * BKK + ((c0 ^ r7) * 8)];
#pragma unroll
            for (int m = 0; m < 4; ++m)
#pragma unroll
                for (int n = 0; n < 4; ++n)
                    acc[m][n] = __builtin_amdgcn_mfma_f32_16x16x32_bf16(
                        a[m], b[n], acc[m][n], 0, 0, 0);
        }
    }

    // ---- epilogue in 2 half-tiles (E = [32][72] per wave; smem stays 32 KB) ----
    __syncthreads();                               // all ds_reads of As/Bs done
    short* E = smem + w * (32 * 72);               // wave-private
    const int cl = lane & 15;
    const int rl = (lane >> 4) * 4;
#pragma unroll
    for (int h = 0; h < 2; ++h) {
#pragma unroll
        for (int n = 0; n < 4; ++n) {
            const int col = (int)brow0 + wc * 64 + n * 16 + cl;
            const float bs = bias[col];
            const int ecol = n * 16 + cl;
#pragma unroll
            for (int ml = 0; ml < 2; ++ml) {
                const int m = h * 2 + ml;
                float g0 = acc[m][n][0] + bs, g1 = acc[m][n][1] + bs;
                float g2 = acc[m][n][2] + bs, g3 = acc[m][n][3] + bs;
                if (GELU) { g0 = gelu_t(g0); g1 = gelu_t(g1); g2 = gelu_t(g2); g3 = gelu_t(g3); }
                unsigned p01, p23;
                asm("v_cvt_pk_bf16_f32 %0, %1, %2" : "=v"(p01) : "v"(g0), "v"(g1));
                asm("v_cvt_pk_bf16_f32 %0, %1, %2" : "=v"(p23) : "v"(g2), "v"(g3));
                const int r0 = ml * 16 + rl;
                E[(r0 + 0) * 72 + ecol] = (short)(p01 & 0xffff);
                E[(r0 + 1) * 72 + ecol] = (short)(p01 >> 16);
                E[(r0 + 2) * 72 + ecol] = (short)(p23 & 0xffff);
                E[(r0 + 3) * 72 + ecol] = (short)(p23 >> 16);
            }
        }
        // wave-private region: LDS ops are in-order within a wave
#pragma unroll
        for (int chunk = 0; chunk < 4; ++chunk) {
            const int rloc = chunk * 8 + (lane >> 3);
            const int c0   = (lane & 7) * 8;
            short8 v = *(const short8*)&E[rloc * 72 + c0];
            *(short8*)&C[(arow0 + wr * 64 + h * 32 + rloc) * 512 + brow0 + wc * 64 + c0] = v;
        }
    }
}

// ---- transpose+convert: dst[n][k] = bf16(src[k][n]), one 512x512 per blockIdx.z ----
__global__ __launch_bounds__(256)
void transpose_conv(const float* __restrict__ src, short* __restrict__ dst) {
    __shared__ float t[32][33];
    const long moff = (long)blockIdx.z * 512 * 512;
    const float* s = src + moff;
    short* d = dst + moff;
    const int tx = threadIdx.x & 31, ty = threadIdx.x >> 5;
    const int bi = blockIdx.x, bj = blockIdx.y;
#pragma unroll
    for (int j = 0; j < 4; ++j)
        t[ty + j * 8][tx] = s[(long)(bi * 32 + ty + j * 8) * 512 + bj * 32 + tx];
    __syncthreads();
#pragma unroll
    for (int j = 0; j < 4; ++j)
        d[(long)(bj * 32 + ty + j * 8) * 512 + bi * 32 + tx] = f2b(t[tx][ty + j * 8]);
}

// ---- f32 -> bf16, writes TWO destinations (X12 slot0 and hA slot0) ----
__global__ __launch_bounds__(256)
void conv_f32_bf16_2(const float* __restrict__ src, short* __restrict__ d1,
                     short* __restrict__ d2, long n) {
    long i = ((long)blockIdx.x * 256 + threadIdx.x) * 4;
    if (i >= n) return;
    float4 f = *(const float4*)&src[i];
    short4v o;
    o[0] = f2b(f.x); o[1] = f2b(f.y); o[2] = f2b(f.z); o[3] = f2b(f.w);
    *(short4v*)&d1[i] = o;
    *(short4v*)&d2[i] = o;
}

// ---- fused LN + L2-normalize + MFMA Gram + logsumexp loss ----
// One wave per sample. Normalized z (bf16) -> wave-private LDS [16][520]
// (rows 12-15 zero), then G = mfma(a,a) over 16 K-steps: A-frag row=lane&15,
// B-frag reads lane-as-column of the SAME data => G = Z Z^T (verified layout).
__global__ __launch_bounds__(256)
void ln_loss(const short* __restrict__ H, const float* __restrict__ g,
             const float* __restrict__ bta, float* __restrict__ out, int CH) {
    __shared__ alignas(16) short Z[4][16 * 520];
    const int wid = threadIdx.x >> 6, lane = threadIdx.x & 63;
    const long b = (long)blockIdx.x * 4 + wid;
    short* Zw = &Z[wid][0];

#pragma unroll
    for (int r = 12; r < 16; ++r)
        *(short8*)&Zw[r * 520 + lane * 8] = (short8){0, 0, 0, 0, 0, 0, 0, 0};

    for (int s = 0; s < 12; ++s) {
        short8 t = *(const short8*)&H[((long)s * CH + b) * 512 + lane * 8];
        float v[8];
        float sum = 0.f, ss = 0.f;
#pragma unroll
        for (int j = 0; j < 8; ++j) { v[j] = b2f(t[j]); sum += v[j]; ss += v[j] * v[j]; }
#pragma unroll
        for (int o = 1; o < 64; o <<= 1) { sum += __shfl_xor(sum, o, 64); ss += __shfl_xor(ss, o, 64); }
        const float mu = sum * (1.f / 512.f);
        const float rs = rsqrtf(ss * (1.f / 512.f) - mu * mu + 1e-5f);
        float y[8]; float nsq = 0.f;
#pragma unroll
        for (int j = 0; j < 8; ++j) {
            const int col = lane * 8 + j;
            y[j] = (v[j] - mu) * rs * g[col] + bta[col];
            nsq += y[j] * y[j];
        }
#pragma unroll
        for (int o = 1; o < 64; o <<= 1) nsq += __shfl_xor(nsq, o, 64);
        const float inv = 1.f / fmaxf(sqrtf(nsq), 1e-8f);
        short8 o8;
#pragma unroll
        for (int j = 0; j < 8; ++j) o8[j] = f2b(y[j] * inv);
        *(short8*)&Zw[s * 520 + lane * 8] = o8;
    }

    // ---- Gram via MFMA (wave-private; within-wave LDS ordering suffices) ----
    f32x4 acc = {0.f, 0.f, 0.f, 0.f};
    const int lr = lane & 15, hi = lane >> 4;
#pragma unroll
    for (int st = 0; st < 16; ++st) {
        short8 a = *(const short8*)&Zw[lr * 520 + st * 32 + hi * 8];
        acc = __builtin_amdgcn_mfma_f32_16x16x32_bf16(a, a, acc, 0, 0, 0);
    }
    // lane (col=lr, hi) holds G[hi*4+i][lr], i=0..3
    const int col = lr;
    float lmax = -3.0e38f;
    bool valid[4];
#pragma unroll
    for (int i = 0; i < 4; ++i) {
        const int row = hi * 4 + i;
        valid[i] = (row < 12) && (row != col);
        if (valid[i]) lmax = fmaxf(lmax, acc[i]);
    }
    lmax = fmaxf(lmax, __shfl_xor(lmax, 16, 64));
    lmax = fmaxf(lmax, __shfl_xor(lmax, 32, 64));
    float esum = 0.f;
#pragma unroll
    for (int i = 0; i < 4; ++i)
        if (valid[i]) esum += __builtin_amdgcn_exp2f((acc[i] - lmax) * 1.44269504f);
    esum += __shfl_xor(esum, 16, 64);
    esum += __shfl_xor(esum, 32, 64);
    // pos = G[0][col], held in acc[0] of the hi==0 lane of this column group
    float contrib = 0.f;
    if (hi == 0 && col >= 1 && col <= 11) {
        const float logden = lmax + __builtin_amdgcn_logf(esum) * 0.6931471806f;
        contrib = acc[0] - logden;
    }
#pragma unroll
    for (int o = 1; o < 16; o <<= 1) contrib += __shfl_xor(contrib, o, 64);
    if (lane == 0) out[b] = -contrib;
}

// ---------------- host ----------------
extern "C" void kernel_launch(void* const* d_in, const int* in_sizes, int n_in,
                              void* d_out, int out_size, void* d_ws, size_t ws_size,
                              hipStream_t stream) {
    const float* x    = (const float*)d_in[0];
    const float* tW1  = (const float*)d_in[1];
    const float* tb1  = (const float*)d_in[2];
    const float* tW2  = (const float*)d_in[3];
    const float* tb2  = (const float*)d_in[4];
    const float* tW3  = (const float*)d_in[5];
    const float* tb3  = (const float*)d_in[6];
    const float* eW1  = (const float*)d_in[7];
    const float* eb1  = (const float*)d_in[8];
    const float* eW2  = (const float*)d_in[9];
    const float* eb2  = (const float*)d_in[10];
    const float* eW3  = (const float*)d_in[11];
    const float* eb3  = (const float*)d_in[12];
    const float* ln_g = (const float*)d_in[13];
    const float* ln_b = (const float*)d_in[14];

    const int  B    = in_sizes[0] / 512;   // 16384
    const long WMAT = 512L * 512L;

    // ---- adaptive chunking: weights + 2 slabs of 12*CH*512 bf16 ----
    int  c  = 1;
    long CH = B;
    for (;;) {
        CH = (long)B / c;
        size_t need = (size_t)36 * WMAT * 2 + (size_t)24 * CH * 512 * 2 + 4096;
        if (need <= ws_size || CH <= 256) break;
        c <<= 1;
    }
    const long SLAB = 12L * CH * 512;

    short* wt  = (short*)d_ws;             // 36 transposed bf16 weight mats
    short* X12 = wt  + 36L * WMAT;         // slab A [12, CH, 512]
    short* hA  = X12 + SLAB;               // slab B [12, CH, 512]

    // --- weight transpose+convert (once) ---
    {
        dim3 tgK(16, 16, 11), tg1(16, 16, 1);
        transpose_conv<<<tgK, 256, 0, stream>>>(tW1, wt + 0L * WMAT);
        transpose_conv<<<tgK, 256, 0, stream>>>(tW2, wt + 11L * WMAT);
        transpose_conv<<<tgK, 256, 0, stream>>>(tW3, wt + 22L * WMAT);
        transpose_conv<<<tg1, 256, 0, stream>>>(eW1, wt + 33L * WMAT);
        transpose_conv<<<tg1, 256, 0, stream>>>(eW2, wt + 34L * WMAT);
        transpose_conv<<<tg1, 256, 0, stream>>>(eW3, wt + 35L * WMAT);
    }

    const long SC = CH * 512;
    const dim3 gT((unsigned)(CH / 32), 1, 11);        // transforms: M = CH
    const dim3 gE((unsigned)(3 * CH / 8), 1, 1);      // encoder: M = 12*CH

    for (int ch = 0; ch < c; ++ch) {
        // x chunk -> bf16 into BOTH X12 slot 0 and hA slot 0
        conv_f32_bf16_2<<<(unsigned)((SC / 4 + 255) / 256), 256, 0, stream>>>(
            x + (long)ch * SC, X12, hA, SC);

        // transforms ping-pong between slabs (slots 1..11)
        gemm_bt<true ><<<gT, 256, 0, stream>>>(hA,        0,  wt + 0L * WMAT,  WMAT, tb1, 512, X12 + SC, SC);
        gemm_bt<true ><<<gT, 256, 0, stream>>>(X12 + SC,  SC, wt + 11L * WMAT, WMAT, tb2, 512, hA + SC,  SC);
        gemm_bt<false><<<gT, 256, 0, stream>>>(hA + SC,   SC, wt + 22L * WMAT, WMAT, tb3, 512, X12 + SC, SC);

        // shared encoder over all 12 views (M = 12*CH), ping-pong slabs
        gemm_bt<true ><<<gE, 256, 0, stream>>>(X12, 0, wt + 33L * WMAT, 0, eb1, 0, hA,  0);
        gemm_bt<true ><<<gE, 256, 0, stream>>>(hA,  0, wt + 34L * WMAT, 0, eb2, 0, X12, 0);
        gemm_bt<false><<<gE, 256, 0, stream>>>(X12, 0, wt + 35L * WMAT, 0, eb3, 0, hA,  0);

        // fused LN + L2-normalize + MFMA Gram + loss
        ln_loss<<<(unsigned)(CH / 4), 256, 0, stream>>>(
            hA, ln_g, ln_b, (float*)d_out + (long)ch * CH, (int)CH);
    }
}

// Round 13
// 1054.405 us; speedup vs baseline: 3.0896x; 1.0730x over previous
//
#include <hip/hip_runtime.h>
#include <hip/hip_bf16.h>
#include <cstdint>

typedef __attribute__((ext_vector_type(8))) short short8;
typedef __attribute__((ext_vector_type(4))) float f32x4;
typedef __attribute__((ext_vector_type(4))) short short4v;

__device__ __forceinline__ float b2f(short s) {
    unsigned u = ((unsigned)(unsigned short)s) << 16;
    return __builtin_bit_cast(float, u);
}
__device__ __forceinline__ short f2b(float f) {
    unsigned u = __builtin_bit_cast(unsigned, f);
    u += 0x7fff + ((u >> 16) & 1);   // RNE
    return (short)(u >> 16);
}

// tanh-form GELU, 8-VALU: gelu = x - x/(1+exp2(x*(c1 + c2*x^2)))
__device__ __forceinline__ float gelu_t(float x) {
    const float c1 = 2.302184829f;     // 2*log2(e)*0.7978845608
    const float c2 = 0.102947246f;     // c1 * 0.044715
    float x2 = x * x;
    float t  = __builtin_fmaf(c2, x2, c1);
    float e  = __builtin_amdgcn_exp2f(x * t);
    return x - __fdividef(x, e + 1.0f);
}

__device__ __forceinline__ void async16(const void* g, void* l) {
    __builtin_amdgcn_global_load_lds(
        (const __attribute__((address_space(1))) unsigned int*)g,
        (__attribute__((address_space(3))) unsigned int*)l, 16, 0, 0);
}

// =====================================================================
// 256x256-tile GEMM, K=512, deep-pipelined (T3+T4):
//  - 8 waves (2 x 4), per-wave output 128x64, 16x16x32 bf16 MFMA
//  - BK=32, TRIPLE-buffered LDS (3 x 32 KB): compute(t) | ready(t+1) | stage(t+2)
//  - raw s_barrier (no vmcnt drain) + counted "s_waitcnt vmcnt(8)"
//  - XOR-swizzled LDS (2-bit key, both-sides), pre-swizzled global source
//  - LDS-tiled epilogue with bias/GELU/cvt_pk, coalesced 16B stores
// =====================================================================
#define NT 16   // K-steps (512 / 32)

template<bool GELU>
__global__ __launch_bounds__(512, 2)
void gemm_bt(const short* __restrict__ A, long sA,
             const short* __restrict__ Bt, long sB,
             const float* __restrict__ bias, long sBias,
             short* __restrict__ C, long sC) {
    const int z = blockIdx.z;
    A    += (long)z * sA;
    Bt   += (long)z * sB;
    bias += (long)z * sBias;
    C    += (long)z * sC;

    // XCD-aware bijective swizzle (nwg multiple of 8 -> simple form; else identity)
    const int nwg = (int)gridDim.x;
    const int bx  = (int)blockIdx.x;
    int flat = bx;
    if ((nwg & 7) == 0) { const int q = nwg >> 3; flat = (bx & 7) * q + (bx >> 3); }
    const long arow0 = (long)(flat >> 1) * 256;
    const long brow0 = (long)(flat & 1) * 256;

    // 3 buffers x (A 256x32 + B 256x32) shorts = 3*16384 shorts = 96 KB
    __shared__ alignas(16) short smem[3 * 16384];

    const int tid  = threadIdx.x;
    const int lane = tid & 63;
    const int w    = tid >> 6;            // 0..7
    const int wrow = w >> 2, wcol = w & 3; // 2x4 wave grid
    const int lr = lane & 15, hi = lane >> 4;

    f32x4 acc[8][4] = {};

    // staging: per thread 4 async16 (2 A + 2 B); LDS dest linear,
    // global source pre-swizzled with key = (row & 3)
    const int rl4 = lane >> 2;                       // 0..15 row-in-16-group
    const int sc  = ((lane & 3) ^ (rl4 & 3)) * 8;    // pre-swizzled chunk (shorts)

    auto stage = [&](int q, int t) {
        short* Ab = smem + q * 16384;
        short* Bb = Ab + 8192;
        const int k0 = t * 32;
#pragma unroll
        for (int j = 0; j < 2; ++j) {
            const int rbase = j * 128 + w * 16;      // wave-uniform
            async16(A  + (arow0 + rbase + rl4) * 512 + k0 + sc, Ab + rbase * 32);
            async16(Bt + (brow0 + rbase + rl4) * 512 + k0 + sc, Bb + rbase * 32);
        }
    };

    stage(0, 0);
    stage(1, 1);

#pragma unroll
    for (int t = 0; t < NT; ++t) {
        if (t + 2 < NT) stage((t + 2) % 3, t + 2);
        // counted wait: stage(t) landed; stage(t+1),(t+2) stay in flight
        if (t + 2 < NT)      asm volatile("s_waitcnt vmcnt(8)" ::: "memory");
        else if (t + 1 < NT) asm volatile("s_waitcnt vmcnt(4)" ::: "memory");
        else                 asm volatile("s_waitcnt vmcnt(0)" ::: "memory");
        __builtin_amdgcn_sched_barrier(0);
        __builtin_amdgcn_s_barrier();    // buf[t] visible to all waves
        __builtin_amdgcn_sched_barrier(0);

        const short* Ab = smem + (t % 3) * 16384;
        const short* Bb = Ab + 8192;
        short8 a[8], b[4];
#pragma unroll
        for (int n = 0; n < 4; ++n) {
            const int r = wcol * 64 + n * 16 + lr;
            b[n] = *(const short8*)&Bb[r * 32 + ((hi ^ (lr & 3)) * 8)];
        }
#pragma unroll
        for (int m = 0; m < 8; ++m) {
            const int r = wrow * 128 + m * 16 + lr;
            a[m] = *(const short8*)&Ab[r * 32 + ((hi ^ (lr & 3)) * 8)];
        }
#pragma unroll
        for (int m = 0; m < 8; ++m)
#pragma unroll
            for (int n = 0; n < 4; ++n)
                acc[m][n] = __builtin_amdgcn_mfma_f32_16x16x32_bf16(
                    a[m], b[n], acc[m][n], 0, 0, 0);

        __builtin_amdgcn_s_barrier();    // all reads of buf[t] done (gates overwrite)
    }

    // ---- epilogue: 4 half-passes of 32 rows; wave-private E = [32][72] ----
    short* E = smem + w * (32 * 72);
    const int cl = lr, rl = hi * 4;
#pragma unroll
    for (int h = 0; h < 4; ++h) {
#pragma unroll
        for (int n = 0; n < 4; ++n) {
            const int col = (int)brow0 + wcol * 64 + n * 16 + cl;
            const float bs = bias[col];
            const int ecol = n * 16 + cl;
#pragma unroll
            for (int ml = 0; ml < 2; ++ml) {
                const int m = h * 2 + ml;
                float g0 = acc[m][n][0] + bs, g1 = acc[m][n][1] + bs;
                float g2 = acc[m][n][2] + bs, g3 = acc[m][n][3] + bs;
                if (GELU) { g0 = gelu_t(g0); g1 = gelu_t(g1); g2 = gelu_t(g2); g3 = gelu_t(g3); }
                unsigned p01, p23;
                asm("v_cvt_pk_bf16_f32 %0, %1, %2" : "=v"(p01) : "v"(g0), "v"(g1));
                asm("v_cvt_pk_bf16_f32 %0, %1, %2" : "=v"(p23) : "v"(g2), "v"(g3));
                const int r0 = ml * 16 + rl;
                E[(r0 + 0) * 72 + ecol] = (short)(p01 & 0xffff);
                E[(r0 + 1) * 72 + ecol] = (short)(p01 >> 16);
                E[(r0 + 2) * 72 + ecol] = (short)(p23 & 0xffff);
                E[(r0 + 3) * 72 + ecol] = (short)(p23 >> 16);
            }
        }
        // wave-private region: LDS ops in-order within a wave
#pragma unroll
        for (int chunk = 0; chunk < 4; ++chunk) {
            const int rloc = chunk * 8 + (lane >> 3);
            const int c0   = (lane & 7) * 8;
            short8 v = *(const short8*)&E[rloc * 72 + c0];
            *(short8*)&C[(arow0 + wrow * 128 + h * 32 + rloc) * 512
                         + brow0 + wcol * 64 + c0] = v;
        }
    }
}

// ---- transpose+convert: dst[n][k] = bf16(src[k][n]), one 512x512 per blockIdx.z ----
__global__ __launch_bounds__(256)
void transpose_conv(const float* __restrict__ src, short* __restrict__ dst) {
    __shared__ float t[32][33];
    const long moff = (long)blockIdx.z * 512 * 512;
    const float* s = src + moff;
    short* d = dst + moff;
    const int tx = threadIdx.x & 31, ty = threadIdx.x >> 5;
    const int bi = blockIdx.x, bj = blockIdx.y;
#pragma unroll
    for (int j = 0; j < 4; ++j)
        t[ty + j * 8][tx] = s[(long)(bi * 32 + ty + j * 8) * 512 + bj * 32 + tx];
    __syncthreads();
#pragma unroll
    for (int j = 0; j < 4; ++j)
        d[(long)(bj * 32 + ty + j * 8) * 512 + bi * 32 + tx] = f2b(t[tx][ty + j * 8]);
}

// ---- f32 -> bf16, writes TWO destinations ----
__global__ __launch_bounds__(256)
void conv_f32_bf16_2(const float* __restrict__ src, short* __restrict__ d1,
                     short* __restrict__ d2, long n) {
    long i = ((long)blockIdx.x * 256 + threadIdx.x) * 4;
    if (i >= n) return;
    float4 f = *(const float4*)&src[i];
    short4v o;
    o[0] = f2b(f.x); o[1] = f2b(f.y); o[2] = f2b(f.z); o[3] = f2b(f.w);
    *(short4v*)&d1[i] = o;
    *(short4v*)&d2[i] = o;
}

// ---- fused LN + L2-normalize + MFMA Gram + logsumexp loss (r12-proven) ----
__global__ __launch_bounds__(256)
void ln_loss(const short* __restrict__ H, const float* __restrict__ g,
             const float* __restrict__ bta, float* __restrict__ out, int CH) {
    __shared__ alignas(16) short Z[4][16 * 520];
    const int wid = threadIdx.x >> 6, lane = threadIdx.x & 63;
    const long b = (long)blockIdx.x * 4 + wid;
    short* Zw = &Z[wid][0];

#pragma unroll
    for (int r = 12; r < 16; ++r)
        *(short8*)&Zw[r * 520 + lane * 8] = (short8){0, 0, 0, 0, 0, 0, 0, 0};

    for (int s = 0; s < 12; ++s) {
        short8 t = *(const short8*)&H[((long)s * CH + b) * 512 + lane * 8];
        float v[8];
        float sum = 0.f, ss = 0.f;
#pragma unroll
        for (int j = 0; j < 8; ++j) { v[j] = b2f(t[j]); sum += v[j]; ss += v[j] * v[j]; }
#pragma unroll
        for (int o = 1; o < 64; o <<= 1) { sum += __shfl_xor(sum, o, 64); ss += __shfl_xor(ss, o, 64); }
        const float mu = sum * (1.f / 512.f);
        const float rs = rsqrtf(ss * (1.f / 512.f) - mu * mu + 1e-5f);
        float y[8]; float nsq = 0.f;
#pragma unroll
        for (int j = 0; j < 8; ++j) {
            const int col = lane * 8 + j;
            y[j] = (v[j] - mu) * rs * g[col] + bta[col];
            nsq += y[j] * y[j];
        }
#pragma unroll
        for (int o = 1; o < 64; o <<= 1) nsq += __shfl_xor(nsq, o, 64);
        const float inv = 1.f / fmaxf(sqrtf(nsq), 1e-8f);
        short8 o8;
#pragma unroll
        for (int j = 0; j < 8; ++j) o8[j] = f2b(y[j] * inv);
        *(short8*)&Zw[s * 520 + lane * 8] = o8;
    }

    f32x4 acc = {0.f, 0.f, 0.f, 0.f};
    const int lr = lane & 15, hi = lane >> 4;
#pragma unroll
    for (int st = 0; st < 16; ++st) {
        short8 a = *(const short8*)&Zw[lr * 520 + st * 32 + hi * 8];
        acc = __builtin_amdgcn_mfma_f32_16x16x32_bf16(a, a, acc, 0, 0, 0);
    }
    const int col = lr;
    float lmax = -3.0e38f;
    bool valid[4];
#pragma unroll
    for (int i = 0; i < 4; ++i) {
        const int row = hi * 4 + i;
        valid[i] = (row < 12) && (row != col);
        if (valid[i]) lmax = fmaxf(lmax, acc[i]);
    }
    lmax = fmaxf(lmax, __shfl_xor(lmax, 16, 64));
    lmax = fmaxf(lmax, __shfl_xor(lmax, 32, 64));
    float esum = 0.f;
#pragma unroll
    for (int i = 0; i < 4; ++i)
        if (valid[i]) esum += __builtin_amdgcn_exp2f((acc[i] - lmax) * 1.44269504f);
    esum += __shfl_xor(esum, 16, 64);
    esum += __shfl_xor(esum, 32, 64);
    float contrib = 0.f;
    if (hi == 0 && col >= 1 && col <= 11) {
        const float logden = lmax + __builtin_amdgcn_logf(esum) * 0.6931471806f;
        contrib = acc[0] - logden;
    }
#pragma unroll
    for (int o = 1; o < 16; o <<= 1) contrib += __shfl_xor(contrib, o, 64);
    if (lane == 0) out[b] = -contrib;
}

// ---------------- host ----------------
extern "C" void kernel_launch(void* const* d_in, const int* in_sizes, int n_in,
                              void* d_out, int out_size, void* d_ws, size_t ws_size,
                              hipStream_t stream) {
    const float* x    = (const float*)d_in[0];
    const float* tW1  = (const float*)d_in[1];
    const float* tb1  = (const float*)d_in[2];
    const float* tW2  = (const float*)d_in[3];
    const float* tb2  = (const float*)d_in[4];
    const float* tW3  = (const float*)d_in[5];
    const float* tb3  = (const float*)d_in[6];
    const float* eW1  = (const float*)d_in[7];
    const float* eb1  = (const float*)d_in[8];
    const float* eW2  = (const float*)d_in[9];
    const float* eb2  = (const float*)d_in[10];
    const float* eW3  = (const float*)d_in[11];
    const float* eb3  = (const float*)d_in[12];
    const float* ln_g = (const float*)d_in[13];
    const float* ln_b = (const float*)d_in[14];

    const int  B    = in_sizes[0] / 512;   // 16384
    const long WMAT = 512L * 512L;

    // ---- adaptive chunking: weights + 2 slabs of 12*CH*512 bf16 ----
    int  c  = 1;
    long CH = B;
    for (;;) {
        CH = (long)B / c;
        size_t need = (size_t)36 * WMAT * 2 + (size_t)24 * CH * 512 * 2 + 4096;
        if (need <= ws_size || CH <= 256) break;
        c <<= 1;
    }
    const long SLAB = 12L * CH * 512;

    short* wt  = (short*)d_ws;             // 36 transposed bf16 weight mats
    short* X12 = wt  + 36L * WMAT;         // slab A [12, CH, 512]
    short* hA  = X12 + SLAB;               // slab B [12, CH, 512]

    // --- weight transpose+convert (once) ---
    {
        dim3 tgK(16, 16, 11), tg1(16, 16, 1);
        transpose_conv<<<tgK, 256, 0, stream>>>(tW1, wt + 0L * WMAT);
        transpose_conv<<<tgK, 256, 0, stream>>>(tW2, wt + 11L * WMAT);
        transpose_conv<<<tgK, 256, 0, stream>>>(tW3, wt + 22L * WMAT);
        transpose_conv<<<tg1, 256, 0, stream>>>(eW1, wt + 33L * WMAT);
        transpose_conv<<<tg1, 256, 0, stream>>>(eW2, wt + 34L * WMAT);
        transpose_conv<<<tg1, 256, 0, stream>>>(eW3, wt + 35L * WMAT);
    }

    const long SC = CH * 512;
    const dim3 gT((unsigned)(CH / 256 * 2), 1, 11);       // transforms: M = CH
    const dim3 gE((unsigned)(12 * CH / 256 * 2), 1, 1);   // encoder: M = 12*CH

    for (int ch = 0; ch < c; ++ch) {
        conv_f32_bf16_2<<<(unsigned)((SC / 4 + 255) / 256), 256, 0, stream>>>(
            x + (long)ch * SC, X12, hA, SC);

        // transforms ping-pong between slabs (slots 1..11)
        gemm_bt<true ><<<gT, 512, 0, stream>>>(hA,        0,  wt + 0L * WMAT,  WMAT, tb1, 512, X12 + SC, SC);
        gemm_bt<true ><<<gT, 512, 0, stream>>>(X12 + SC,  SC, wt + 11L * WMAT, WMAT, tb2, 512, hA + SC,  SC);
        gemm_bt<false><<<gT, 512, 0, stream>>>(hA + SC,   SC, wt + 22L * WMAT, WMAT, tb3, 512, X12 + SC, SC);

        // shared encoder over all 12 views (M = 12*CH), ping-pong slabs
        gemm_bt<true ><<<gE, 512, 0, stream>>>(X12, 0, wt + 33L * WMAT, 0, eb1, 0, hA,  0);
        gemm_bt<true ><<<gE, 512, 0, stream>>>(hA,  0, wt + 34L * WMAT, 0, eb2, 0, X12, 0);
        gemm_bt<false><<<gE, 512, 0, stream>>>(X12, 0, wt + 35L * WMAT, 0, eb3, 0, hA,  0);

        // fused LN + L2-normalize + MFMA Gram + loss
        ln_loss<<<(unsigned)(CH / 4), 256, 0, stream>>>(
            hA, ln_g, ln_b, (float*)d_out + (long)ch * CH, (int)CH);
    }
}

// Round 14
// 1000.502 us; speedup vs baseline: 3.2560x; 1.0539x over previous
//
#include <hip/hip_runtime.h>
#include <hip/hip_bf16.h>
#include <cstdint>

typedef __attribute__((ext_vector_type(8))) short short8;
typedef __attribute__((ext_vector_type(4))) float f32x4;
typedef __attribute__((ext_vector_type(4))) short short4v;

__device__ __forceinline__ float b2f(short s) {
    unsigned u = ((unsigned)(unsigned short)s) << 16;
    return __builtin_bit_cast(float, u);
}
__device__ __forceinline__ short f2b(float f) {
    unsigned u = __builtin_bit_cast(unsigned, f);
    u += 0x7fff + ((u >> 16) & 1);   // RNE
    return (short)(u >> 16);
}

// tanh-form GELU, 8-VALU: gelu = x - x/(1+exp2(x*(c1 + c2*x^2)))
__device__ __forceinline__ float gelu_t(float x) {
    const float c1 = 2.302184829f;     // 2*log2(e)*0.7978845608
    const float c2 = 0.102947246f;     // c1 * 0.044715
    float x2 = x * x;
    float t  = __builtin_fmaf(c2, x2, c1);
    float e  = __builtin_amdgcn_exp2f(x * t);
    return x - __fdividef(x, e + 1.0f);
}

__device__ __forceinline__ void async16(const void* g, void* l) {
    __builtin_amdgcn_global_load_lds(
        (const __attribute__((address_space(1))) unsigned int*)g,
        (__attribute__((address_space(3))) unsigned int*)l, 16, 0, 0);
}

// =====================================================================
// 256x256-tile GEMM, K=512, counted-vmcnt pipeline (T3-min + T4 + T5):
//  - 8 waves (2 x 4), per-wave output 128x64, 16x16x32 bf16 MFMA
//  - BK=64, DOUBLE-buffered LDS (2 x 64 KB): stage(t+1) in flight over compute(t)
//  - raw s_barrier + literal "s_waitcnt vmcnt(8)" (never 0 mid-loop)
//  - 128-B LDS rows + 3-bit XOR key (r12-proven conflict-free geometry)
//  - s_setprio(1) around each 32-MFMA cluster
// =====================================================================
#define NT 8    // K-tiles (512 / 64)

template<bool GELU>
__global__ __launch_bounds__(512, 2)
void gemm_bt(const short* __restrict__ A, long sA,
             const short* __restrict__ Bt, long sB,
             const float* __restrict__ bias, long sBias,
             short* __restrict__ C, long sC) {
    const int z = blockIdx.z;
    A    += (long)z * sA;
    Bt   += (long)z * sB;
    bias += (long)z * sBias;
    C    += (long)z * sC;

    // XCD-aware bijective swizzle (nwg multiple of 8 -> chunked form)
    const int nwg = (int)gridDim.x;
    const int bx  = (int)blockIdx.x;
    int flat = bx;
    if ((nwg & 7) == 0) { const int q = nwg >> 3; flat = (bx & 7) * q + (bx >> 3); }
    const long arow0 = (long)(flat >> 1) * 256;
    const long brow0 = (long)(flat & 1) * 256;

    // 2 buffers x (A 256x64 + B 256x64) shorts = 131072 B
    __shared__ alignas(16) short smem[2 * 2 * 256 * 64];

    const int tid  = threadIdx.x;
    const int lane = tid & 63;
    const int w    = tid >> 6;             // 0..7
    const int wrow = w >> 2, wcol = w & 3; // 2x4 wave grid
    const int lr = lane & 15, hi = lane >> 4;

    f32x4 acc[8][4] = {};

    // staging: 8 async16/thread/tile; rows 128 B; src pre-swizzled key=(row&7)
    const int srow = lane >> 3;                    // 0..7
    const int sc   = ((lane & 7) ^ srow) * 8;      // pre-swizzled chunk (shorts)

    auto stage = [&](int q, int t) {
        short* Ab = smem + q * 32768;
        short* Bb = Ab + 16384;
        const int k0 = t * 64;
#pragma unroll
        for (int j = 0; j < 4; ++j) {
            const int rbase = j * 64 + w * 8;      // wave-uniform
            async16(A  + (arow0 + rbase + srow) * 512 + k0 + sc, Ab + rbase * 64);
            async16(Bt + (brow0 + rbase + srow) * 512 + k0 + sc, Bb + rbase * 64);
        }
    };

    stage(0, 0);

    int buf = 0;
#pragma unroll
    for (int t = 0; t < NT; ++t) {
        if (t + 1 < NT) {
            stage(buf ^ 1, t + 1);
            asm volatile("s_waitcnt vmcnt(8)" ::: "memory");   // tile t landed; t+1 in flight
        } else {
            asm volatile("s_waitcnt vmcnt(0)" ::: "memory");
        }
        __builtin_amdgcn_sched_barrier(0);
        __builtin_amdgcn_s_barrier();    // buf[t] visible to all waves
        __builtin_amdgcn_sched_barrier(0);

        const short* Ab = smem + buf * 32768;
        const short* Bb = Ab + 16384;
#pragma unroll
        for (int ks = 0; ks < 2; ++ks) {
            const int ch = ks * 4 + hi;            // global 16B-chunk index
            short8 a[8], b[4];
#pragma unroll
            for (int n = 0; n < 4; ++n) {
                const int r = wcol * 64 + n * 16 + lr;
                b[n] = *(const short8*)&Bb[r * 64 + ((ch ^ (r & 7)) * 8)];
            }
#pragma unroll
            for (int m = 0; m < 8; ++m) {
                const int r = wrow * 128 + m * 16 + lr;
                a[m] = *(const short8*)&Ab[r * 64 + ((ch ^ (r & 7)) * 8)];
            }
            __builtin_amdgcn_s_setprio(1);
#pragma unroll
            for (int m = 0; m < 8; ++m)
#pragma unroll
                for (int n = 0; n < 4; ++n)
                    acc[m][n] = __builtin_amdgcn_mfma_f32_16x16x32_bf16(
                        a[m], b[n], acc[m][n], 0, 0, 0);
            __builtin_amdgcn_s_setprio(0);
        }

        __builtin_amdgcn_s_barrier();    // all reads of buf[t] done (gates overwrite)
        buf ^= 1;
    }

    // ---- epilogue: 4 half-passes of 32 rows; wave-private E = [32][72] ----
    short* E = smem + w * (32 * 72);
    const int cl = lr, rl = hi * 4;
#pragma unroll
    for (int h = 0; h < 4; ++h) {
#pragma unroll
        for (int n = 0; n < 4; ++n) {
            const int col = (int)brow0 + wcol * 64 + n * 16 + cl;
            const float bs = bias[col];
            const int ecol = n * 16 + cl;
#pragma unroll
            for (int ml = 0; ml < 2; ++ml) {
                const int m = h * 2 + ml;
                float g0 = acc[m][n][0] + bs, g1 = acc[m][n][1] + bs;
                float g2 = acc[m][n][2] + bs, g3 = acc[m][n][3] + bs;
                if (GELU) { g0 = gelu_t(g0); g1 = gelu_t(g1); g2 = gelu_t(g2); g3 = gelu_t(g3); }
                unsigned p01, p23;
                asm("v_cvt_pk_bf16_f32 %0, %1, %2" : "=v"(p01) : "v"(g0), "v"(g1));
                asm("v_cvt_pk_bf16_f32 %0, %1, %2" : "=v"(p23) : "v"(g2), "v"(g3));
                const int r0 = ml * 16 + rl;
                E[(r0 + 0) * 72 + ecol] = (short)(p01 & 0xffff);
                E[(r0 + 1) * 72 + ecol] = (short)(p01 >> 16);
                E[(r0 + 2) * 72 + ecol] = (short)(p23 & 0xffff);
                E[(r0 + 3) * 72 + ecol] = (short)(p23 >> 16);
            }
        }
        // wave-private region: LDS ops in-order within a wave
#pragma unroll
        for (int chunk = 0; chunk < 4; ++chunk) {
            const int rloc = chunk * 8 + (lane >> 3);
            const int c0   = (lane & 7) * 8;
            short8 v = *(const short8*)&E[rloc * 72 + c0];
            *(short8*)&C[(arow0 + wrow * 128 + h * 32 + rloc) * 512
                         + brow0 + wcol * 64 + c0] = v;
        }
    }
}

// ---- transpose+convert: dst[n][k] = bf16(src[k][n]), one 512x512 per blockIdx.z ----
__global__ __launch_bounds__(256)
void transpose_conv(const float* __restrict__ src, short* __restrict__ dst) {
    __shared__ float t[32][33];
    const long moff = (long)blockIdx.z * 512 * 512;
    const float* s = src + moff;
    short* d = dst + moff;
    const int tx = threadIdx.x & 31, ty = threadIdx.x >> 5;
    const int bi = blockIdx.x, bj = blockIdx.y;
#pragma unroll
    for (int j = 0; j < 4; ++j)
        t[ty + j * 8][tx] = s[(long)(bi * 32 + ty + j * 8) * 512 + bj * 32 + tx];
    __syncthreads();
#pragma unroll
    for (int j = 0; j < 4; ++j)
        d[(long)(bj * 32 + ty + j * 8) * 512 + bi * 32 + tx] = f2b(t[tx][ty + j * 8]);
}

// ---- f32 -> bf16, writes TWO destinations ----
__global__ __launch_bounds__(256)
void conv_f32_bf16_2(const float* __restrict__ src, short* __restrict__ d1,
                     short* __restrict__ d2, long n) {
    long i = ((long)blockIdx.x * 256 + threadIdx.x) * 4;
    if (i >= n) return;
    float4 f = *(const float4*)&src[i];
    short4v o;
    o[0] = f2b(f.x); o[1] = f2b(f.y); o[2] = f2b(f.z); o[3] = f2b(f.w);
    *(short4v*)&d1[i] = o;
    *(short4v*)&d2[i] = o;
}

// ---- fused LN + L2-normalize + MFMA Gram + logsumexp loss (r12-proven) ----
__global__ __launch_bounds__(256)
void ln_loss(const short* __restrict__ H, const float* __restrict__ g,
             const float* __restrict__ bta, float* __restrict__ out, int CH) {
    __shared__ alignas(16) short Z[4][16 * 520];
    const int wid = threadIdx.x >> 6, lane = threadIdx.x & 63;
    const long b = (long)blockIdx.x * 4 + wid;
    short* Zw = &Z[wid][0];

#pragma unroll
    for (int r = 12; r < 16; ++r)
        *(short8*)&Zw[r * 520 + lane * 8] = (short8){0, 0, 0, 0, 0, 0, 0, 0};

    for (int s = 0; s < 12; ++s) {
        short8 t = *(const short8*)&H[((long)s * CH + b) * 512 + lane * 8];
        float v[8];
        float sum = 0.f, ss = 0.f;
#pragma unroll
        for (int j = 0; j < 8; ++j) { v[j] = b2f(t[j]); sum += v[j]; ss += v[j] * v[j]; }
#pragma unroll
        for (int o = 1; o < 64; o <<= 1) { sum += __shfl_xor(sum, o, 64); ss += __shfl_xor(ss, o, 64); }
        const float mu = sum * (1.f / 512.f);
        const float rs = rsqrtf(ss * (1.f / 512.f) - mu * mu + 1e-5f);
        float y[8]; float nsq = 0.f;
#pragma unroll
        for (int j = 0; j < 8; ++j) {
            const int col = lane * 8 + j;
            y[j] = (v[j] - mu) * rs * g[col] + bta[col];
            nsq += y[j] * y[j];
        }
#pragma unroll
        for (int o = 1; o < 64; o <<= 1) nsq += __shfl_xor(nsq, o, 64);
        const float inv = 1.f / fmaxf(sqrtf(nsq), 1e-8f);
        short8 o8;
#pragma unroll
        for (int j = 0; j < 8; ++j) o8[j] = f2b(y[j] * inv);
        *(short8*)&Zw[s * 520 + lane * 8] = o8;
    }

    f32x4 acc = {0.f, 0.f, 0.f, 0.f};
    const int lr = lane & 15, hi = lane >> 4;
#pragma unroll
    for (int st = 0; st < 16; ++st) {
        short8 a = *(const short8*)&Zw[lr * 520 + st * 32 + hi * 8];
        acc = __builtin_amdgcn_mfma_f32_16x16x32_bf16(a, a, acc, 0, 0, 0);
    }
    const int col = lr;
    float lmax = -3.0e38f;
    bool valid[4];
#pragma unroll
    for (int i = 0; i < 4; ++i) {
        const int row = hi * 4 + i;
        valid[i] = (row < 12) && (row != col);
        if (valid[i]) lmax = fmaxf(lmax, acc[i]);
    }
    lmax = fmaxf(lmax, __shfl_xor(lmax, 16, 64));
    lmax = fmaxf(lmax, __shfl_xor(lmax, 32, 64));
    float esum = 0.f;
#pragma unroll
    for (int i = 0; i < 4; ++i)
        if (valid[i]) esum += __builtin_amdgcn_exp2f((acc[i] - lmax) * 1.44269504f);
    esum += __shfl_xor(esum, 16, 64);
    esum += __shfl_xor(esum, 32, 64);
    float contrib = 0.f;
    if (hi == 0 && col >= 1 && col <= 11) {
        const float logden = lmax + __builtin_amdgcn_logf(esum) * 0.6931471806f;
        contrib = acc[0] - logden;
    }
#pragma unroll
    for (int o = 1; o < 16; o <<= 1) contrib += __shfl_xor(contrib, o, 64);
    if (lane == 0) out[b] = -contrib;
}

// ---------------- host ----------------
extern "C" void kernel_launch(void* const* d_in, const int* in_sizes, int n_in,
                              void* d_out, int out_size, void* d_ws, size_t ws_size,
                              hipStream_t stream) {
    const float* x    = (const float*)d_in[0];
    const float* tW1  = (const float*)d_in[1];
    const float* tb1  = (const float*)d_in[2];
    const float* tW2  = (const float*)d_in[3];
    const float* tb2  = (const float*)d_in[4];
    const float* tW3  = (const float*)d_in[5];
    const float* tb3  = (const float*)d_in[6];
    const float* eW1  = (const float*)d_in[7];
    const float* eb1  = (const float*)d_in[8];
    const float* eW2  = (const float*)d_in[9];
    const float* eb2  = (const float*)d_in[10];
    const float* eW3  = (const float*)d_in[11];
    const float* eb3  = (const float*)d_in[12];
    const float* ln_g = (const float*)d_in[13];
    const float* ln_b = (const float*)d_in[14];

    const int  B    = in_sizes[0] / 512;   // 16384
    const long WMAT = 512L * 512L;

    // ---- adaptive chunking: weights + 2 slabs of 12*CH*512 bf16 ----
    int  c  = 1;
    long CH = B;
    for (;;) {
        CH = (long)B / c;
        size_t need = (size_t)36 * WMAT * 2 + (size_t)24 * CH * 512 * 2 + 4096;
        if (need <= ws_size || CH <= 256) break;
        c <<= 1;
    }
    const long SLAB = 12L * CH * 512;

    short* wt  = (short*)d_ws;             // 36 transposed bf16 weight mats
    short* X12 = wt  + 36L * WMAT;         // slab A [12, CH, 512]
    short* hA  = X12 + SLAB;               // slab B [12, CH, 512]

    // --- weight transpose+convert (once) ---
    {
        dim3 tgK(16, 16, 11), tg1(16, 16, 1);
        transpose_conv<<<tgK, 256, 0, stream>>>(tW1, wt + 0L * WMAT);
        transpose_conv<<<tgK, 256, 0, stream>>>(tW2, wt + 11L * WMAT);
        transpose_conv<<<tgK, 256, 0, stream>>>(tW3, wt + 22L * WMAT);
        transpose_conv<<<tg1, 256, 0, stream>>>(eW1, wt + 33L * WMAT);
        transpose_conv<<<tg1, 256, 0, stream>>>(eW2, wt + 34L * WMAT);
        transpose_conv<<<tg1, 256, 0, stream>>>(eW3, wt + 35L * WMAT);
    }

    const long SC = CH * 512;
    const dim3 gT((unsigned)(CH / 256 * 2), 1, 11);       // transforms: M = CH
    const dim3 gE((unsigned)(12 * CH / 256 * 2), 1, 1);   // encoder: M = 12*CH

    for (int ch = 0; ch < c; ++ch) {
        conv_f32_bf16_2<<<(unsigned)((SC / 4 + 255) / 256), 256, 0, stream>>>(
            x + (long)ch * SC, X12, hA, SC);

        // transforms ping-pong between slabs (slots 1..11)
        gemm_bt<true ><<<gT, 512, 0, stream>>>(hA,        0,  wt + 0L * WMAT,  WMAT, tb1, 512, X12 + SC, SC);
        gemm_bt<true ><<<gT, 512, 0, stream>>>(X12 + SC,  SC, wt + 11L * WMAT, WMAT, tb2, 512, hA + SC,  SC);
        gemm_bt<false><<<gT, 512, 0, stream>>>(hA + SC,   SC, wt + 22L * WMAT, WMAT, tb3, 512, X12 + SC, SC);

        // shared encoder over all 12 views (M = 12*CH), ping-pong slabs
        gemm_bt<true ><<<gE, 512, 0, stream>>>(X12, 0, wt + 33L * WMAT, 0, eb1, 0, hA,  0);
        gemm_bt<true ><<<gE, 512, 0, stream>>>(hA,  0, wt + 34L * WMAT, 0, eb2, 0, X12, 0);
        gemm_bt<false><<<gE, 512, 0, stream>>>(X12, 0, wt + 35L * WMAT, 0, eb3, 0, hA,  0);

        // fused LN + L2-normalize + MFMA Gram + loss
        ln_loss<<<(unsigned)(CH / 4), 256, 0, stream>>>(
            hA, ln_g, ln_b, (float*)d_out + (long)ch * CH, (int)CH);
    }
}

// Round 15
// 911.165 us; speedup vs baseline: 3.5753x; 1.0980x over previous
//
#include <hip/hip_runtime.h>
#include <hip/hip_bf16.h>
#include <cstdint>

typedef __attribute__((ext_vector_type(8))) short short8;
typedef __attribute__((ext_vector_type(4))) float f32x4;
typedef __attribute__((ext_vector_type(4))) short short4v;

__device__ __forceinline__ float b2f(short s) {
    unsigned u = ((unsigned)(unsigned short)s) << 16;
    return __builtin_bit_cast(float, u);
}
__device__ __forceinline__ short f2b(float f) {
    unsigned u = __builtin_bit_cast(unsigned, f);
    u += 0x7fff + ((u >> 16) & 1);   // RNE
    return (short)(u >> 16);
}

// tanh-form GELU, 8-VALU: gelu = x - x/(1+exp2(x*(c1 + c2*x^2)))
__device__ __forceinline__ float gelu_t(float x) {
    const float c1 = 2.302184829f;     // 2*log2(e)*0.7978845608
    const float c2 = 0.102947246f;     // c1 * 0.044715
    float x2 = x * x;
    float t  = __builtin_fmaf(c2, x2, c1);
    float e  = __builtin_amdgcn_exp2f(x * t);
    return x - __fdividef(x, e + 1.0f);
}

__device__ __forceinline__ void async16(const void* g, void* l) {
    __builtin_amdgcn_global_load_lds(
        (const __attribute__((address_space(1))) unsigned int*)g,
        (__attribute__((address_space(3))) unsigned int*)l, 16, 0, 0);
}

// ===== 256x256-tile GEMM, K=512, counted-vmcnt pipeline (r14-proven) =====
#define NT 8    // K-tiles (512 / 64)

template<bool GELU>
__global__ __launch_bounds__(512, 2)
void gemm_bt(const short* __restrict__ A, long sA,
             const short* __restrict__ Bt, long sB,
             const float* __restrict__ bias, long sBias,
             short* __restrict__ C, long sC) {
    const int z = blockIdx.z;
    A    += (long)z * sA;
    Bt   += (long)z * sB;
    bias += (long)z * sBias;
    C    += (long)z * sC;

    const int nwg = (int)gridDim.x;
    const int bx  = (int)blockIdx.x;
    int flat = bx;
    if ((nwg & 7) == 0) { const int q = nwg >> 3; flat = (bx & 7) * q + (bx >> 3); }
    const long arow0 = (long)(flat >> 1) * 256;
    const long brow0 = (long)(flat & 1) * 256;

    __shared__ alignas(16) short smem[2 * 2 * 256 * 64];

    const int tid  = threadIdx.x;
    const int lane = tid & 63;
    const int w    = tid >> 6;
    const int wrow = w >> 2, wcol = w & 3;
    const int lr = lane & 15, hi = lane >> 4;

    f32x4 acc[8][4] = {};

    const int srow = lane >> 3;
    const int sc   = ((lane & 7) ^ srow) * 8;

    auto stage = [&](int q, int t) {
        short* Ab = smem + q * 32768;
        short* Bb = Ab + 16384;
        const int k0 = t * 64;
#pragma unroll
        for (int j = 0; j < 4; ++j) {
            const int rbase = j * 64 + w * 8;
            async16(A  + (arow0 + rbase + srow) * 512 + k0 + sc, Ab + rbase * 64);
            async16(Bt + (brow0 + rbase + srow) * 512 + k0 + sc, Bb + rbase * 64);
        }
    };

    stage(0, 0);

    int buf = 0;
#pragma unroll
    for (int t = 0; t < NT; ++t) {
        if (t + 1 < NT) {
            stage(buf ^ 1, t + 1);
            asm volatile("s_waitcnt vmcnt(8)" ::: "memory");
        } else {
            asm volatile("s_waitcnt vmcnt(0)" ::: "memory");
        }
        __builtin_amdgcn_sched_barrier(0);
        __builtin_amdgcn_s_barrier();
        __builtin_amdgcn_sched_barrier(0);

        const short* Ab = smem + buf * 32768;
        const short* Bb = Ab + 16384;
#pragma unroll
        for (int ks = 0; ks < 2; ++ks) {
            const int ch = ks * 4 + hi;
            short8 a[8], b[4];
#pragma unroll
            for (int n = 0; n < 4; ++n) {
                const int r = wcol * 64 + n * 16 + lr;
                b[n] = *(const short8*)&Bb[r * 64 + ((ch ^ (r & 7)) * 8)];
            }
#pragma unroll
            for (int m = 0; m < 8; ++m) {
                const int r = wrow * 128 + m * 16 + lr;
                a[m] = *(const short8*)&Ab[r * 64 + ((ch ^ (r & 7)) * 8)];
            }
            __builtin_amdgcn_s_setprio(1);
#pragma unroll
            for (int m = 0; m < 8; ++m)
#pragma unroll
                for (int n = 0; n < 4; ++n)
                    acc[m][n] = __builtin_amdgcn_mfma_f32_16x16x32_bf16(
                        a[m], b[n], acc[m][n], 0, 0, 0);
            __builtin_amdgcn_s_setprio(0);
        }

        __builtin_amdgcn_s_barrier();
        buf ^= 1;
    }

    // ---- epilogue: 4 half-passes of 32 rows; wave-private E = [32][72] ----
    short* E = smem + w * (32 * 72);
    const int cl = lr, rl = hi * 4;
#pragma unroll
    for (int h = 0; h < 4; ++h) {
#pragma unroll
        for (int n = 0; n < 4; ++n) {
            const int col = (int)brow0 + wcol * 64 + n * 16 + cl;
            const float bs = bias[col];
            const int ecol = n * 16 + cl;
#pragma unroll
            for (int ml = 0; ml < 2; ++ml) {
                const int m = h * 2 + ml;
                float g0 = acc[m][n][0] + bs, g1 = acc[m][n][1] + bs;
                float g2 = acc[m][n][2] + bs, g3 = acc[m][n][3] + bs;
                if (GELU) { g0 = gelu_t(g0); g1 = gelu_t(g1); g2 = gelu_t(g2); g3 = gelu_t(g3); }
                unsigned p01, p23;
                asm("v_cvt_pk_bf16_f32 %0, %1, %2" : "=v"(p01) : "v"(g0), "v"(g1));
                asm("v_cvt_pk_bf16_f32 %0, %1, %2" : "=v"(p23) : "v"(g2), "v"(g3));
                const int r0 = ml * 16 + rl;
                E[(r0 + 0) * 72 + ecol] = (short)(p01 & 0xffff);
                E[(r0 + 1) * 72 + ecol] = (short)(p01 >> 16);
                E[(r0 + 2) * 72 + ecol] = (short)(p23 & 0xffff);
                E[(r0 + 3) * 72 + ecol] = (short)(p23 >> 16);
            }
        }
#pragma unroll
        for (int chunk = 0; chunk < 4; ++chunk) {
            const int rloc = chunk * 8 + (lane >> 3);
            const int c0   = (lane & 7) * 8;
            short8 v = *(const short8*)&E[rloc * 72 + c0];
            *(short8*)&C[(arow0 + wrow * 128 + h * 32 + rloc) * 512
                         + brow0 + wcol * 64 + c0] = v;
        }
    }
}

// ---- transpose+convert: dst[n][k] = bf16(src[k][n]), one 512x512 per blockIdx.z ----
__global__ __launch_bounds__(256)
void transpose_conv(const float* __restrict__ src, short* __restrict__ dst) {
    __shared__ float t[32][33];
    const long moff = (long)blockIdx.z * 512 * 512;
    const float* s = src + moff;
    short* d = dst + moff;
    const int tx = threadIdx.x & 31, ty = threadIdx.x >> 5;
    const int bi = blockIdx.x, bj = blockIdx.y;
#pragma unroll
    for (int j = 0; j < 4; ++j)
        t[ty + j * 8][tx] = s[(long)(bi * 32 + ty + j * 8) * 512 + bj * 32 + tx];
    __syncthreads();
#pragma unroll
    for (int j = 0; j < 4; ++j)
        d[(long)(bj * 32 + ty + j * 8) * 512 + bi * 32 + tx] = f2b(t[tx][ty + j * 8]);
}

// ---- f32 -> bf16 elementwise ----
__global__ __launch_bounds__(256)
void conv_f32_bf16(const float* __restrict__ src, short* __restrict__ dst, long n) {
    long i = ((long)blockIdx.x * 256 + threadIdx.x) * 4;
    if (i >= n) return;
    float4 f = *(const float4*)&src[i];
    short4v o;
    o[0] = f2b(f.x); o[1] = f2b(f.y); o[2] = f2b(f.z); o[3] = f2b(f.w);
    *(short4v*)&dst[i] = o;
}

// ---- bias fold: bB[(k+1)*512+n] = dot(tb3_k, eW1[:,n]) + eb1[n]  (one wave per (k,n)) ----
__global__ __launch_bounds__(256)
void bias_fold(const float* __restrict__ tb3, const short* __restrict__ wtE1,
               const float* __restrict__ eb1, float* __restrict__ bB) {
    const int wid = threadIdx.x >> 6, lane = threadIdx.x & 63;
    const int idx = blockIdx.x * 4 + wid;        // 0 .. 11*512-1
    const int k = idx >> 9, n = idx & 511;
    short8 wv = *(const short8*)&wtE1[(long)n * 512 + lane * 8];
    const float* tb = tb3 + (long)k * 512 + lane * 8;
    float s = 0.f;
#pragma unroll
    for (int j = 0; j < 8; ++j) s += b2f(wv[j]) * tb[j];
#pragma unroll
    for (int o = 1; o < 64; o <<= 1) s += __shfl_xor(s, o, 64);
    if (lane == 0) bB[(long)(k + 1) * 512 + n] = s + eb1[n];
}

// ---- fused LN + L2-normalize + MFMA Gram + logsumexp loss (r12-proven) ----
__global__ __launch_bounds__(256)
void ln_loss(const short* __restrict__ H, const float* __restrict__ g,
             const float* __restrict__ bta, float* __restrict__ out, int CH) {
    __shared__ alignas(16) short Z[4][16 * 520];
    const int wid = threadIdx.x >> 6, lane = threadIdx.x & 63;
    const long b = (long)blockIdx.x * 4 + wid;
    short* Zw = &Z[wid][0];

#pragma unroll
    for (int r = 12; r < 16; ++r)
        *(short8*)&Zw[r * 520 + lane * 8] = (short8){0, 0, 0, 0, 0, 0, 0, 0};

    for (int s = 0; s < 12; ++s) {
        short8 t = *(const short8*)&H[((long)s * CH + b) * 512 + lane * 8];
        float v[8];
        float sum = 0.f, ss = 0.f;
#pragma unroll
        for (int j = 0; j < 8; ++j) { v[j] = b2f(t[j]); sum += v[j]; ss += v[j] * v[j]; }
#pragma unroll
        for (int o = 1; o < 64; o <<= 1) { sum += __shfl_xor(sum, o, 64); ss += __shfl_xor(ss, o, 64); }
        const float mu = sum * (1.f / 512.f);
        const float rs = rsqrtf(ss * (1.f / 512.f) - mu * mu + 1e-5f);
        float y[8]; float nsq = 0.f;
#pragma unroll
        for (int j = 0; j < 8; ++j) {
            const int col = lane * 8 + j;
            y[j] = (v[j] - mu) * rs * g[col] + bta[col];
            nsq += y[j] * y[j];
        }
#pragma unroll
        for (int o = 1; o < 64; o <<= 1) nsq += __shfl_xor(nsq, o, 64);
        const float inv = 1.f / fmaxf(sqrtf(nsq), 1e-8f);
        short8 o8;
#pragma unroll
        for (int j = 0; j < 8; ++j) o8[j] = f2b(y[j] * inv);
        *(short8*)&Zw[s * 520 + lane * 8] = o8;
    }

    f32x4 acc = {0.f, 0.f, 0.f, 0.f};
    const int lr = lane & 15, hi = lane >> 4;
#pragma unroll
    for (int st = 0; st < 16; ++st) {
        short8 a = *(const short8*)&Zw[lr * 520 + st * 32 + hi * 8];
        acc = __builtin_amdgcn_mfma_f32_16x16x32_bf16(a, a, acc, 0, 0, 0);
    }
    const int col = lr;
    float lmax = -3.0e38f;
    bool valid[4];
#pragma unroll
    for (int i = 0; i < 4; ++i) {
        const int row = hi * 4 + i;
        valid[i] = (row < 12) && (row != col);
        if (valid[i]) lmax = fmaxf(lmax, acc[i]);
    }
    lmax = fmaxf(lmax, __shfl_xor(lmax, 16, 64));
    lmax = fmaxf(lmax, __shfl_xor(lmax, 32, 64));
    float esum = 0.f;
#pragma unroll
    for (int i = 0; i < 4; ++i)
        if (valid[i]) esum += __builtin_amdgcn_exp2f((acc[i] - lmax) * 1.44269504f);
    esum += __shfl_xor(esum, 16, 64);
    esum += __shfl_xor(esum, 32, 64);
    float contrib = 0.f;
    if (hi == 0 && col >= 1 && col <= 11) {
        const float logden = lmax + __builtin_amdgcn_logf(esum) * 0.6931471806f;
        contrib = acc[0] - logden;
    }
#pragma unroll
    for (int o = 1; o < 16; o <<= 1) contrib += __shfl_xor(contrib, o, 64);
    if (lane == 0) out[b] = -contrib;
}

// ---------------- host ----------------
extern "C" void kernel_launch(void* const* d_in, const int* in_sizes, int n_in,
                              void* d_out, int out_size, void* d_ws, size_t ws_size,
                              hipStream_t stream) {
    const float* x    = (const float*)d_in[0];
    const float* tW1  = (const float*)d_in[1];
    const float* tb1  = (const float*)d_in[2];
    const float* tW2  = (const float*)d_in[3];
    const float* tb2  = (const float*)d_in[4];
    const float* tW3  = (const float*)d_in[5];
    const float* tb3  = (const float*)d_in[6];
    const float* eW1  = (const float*)d_in[7];
    const float* eb1  = (const float*)d_in[8];
    const float* eW2  = (const float*)d_in[9];
    const float* eb2  = (const float*)d_in[10];
    const float* eW3  = (const float*)d_in[11];
    const float* eb3  = (const float*)d_in[12];
    const float* ln_g = (const float*)d_in[13];
    const float* ln_b = (const float*)d_in[14];

    const int  B    = in_sizes[0] / 512;   // 16384
    const long WMAT = 512L * 512L;

    // ---- adaptive chunking: wt(36) + Mt(12) bf16 + bias bufs + 2 slabs bf16 ----
    int  c  = 1;
    long CH = B;
    for (;;) {
        CH = (long)B / c;
        size_t need = (size_t)48 * WMAT * 2 + (512 + 12 * 512) * 4
                    + (size_t)24 * CH * 512 * 2 + 8192;
        if (need <= ws_size || CH <= 256) break;
        c <<= 1;
    }
    const long SLAB = 12L * CH * 512;

    short* wt   = (short*)d_ws;             // 0..21: tW1^T,tW2^T; 22..32: tW3 (orig, bf16); 33..35: eW^T
    short* Mt   = wt + 36L * WMAT;          // 12 mats: slot0 = eW1^T copy, 1..11 = (tW3_k·eW1)^T
    float* zero512 = (float*)(Mt + 12L * WMAT);
    float* bB   = zero512 + 512;            // 12x512: row0 = eb1, 1..11 = folded biases
    short* S    = (short*)(bB + 12 * 512);  // slab S [12, CH, 512]
    short* T    = S + SLAB;                 // slab T [12, CH, 512]

    // --- weight prep (once per launch) ---
    {
        dim3 tgK(16, 16, 11), tg1(16, 16, 1);
        transpose_conv<<<tgK, 256, 0, stream>>>(tW1, wt + 0L * WMAT);
        transpose_conv<<<tgK, 256, 0, stream>>>(tW2, wt + 11L * WMAT);
        conv_f32_bf16<<<(unsigned)((11 * WMAT / 4 + 255) / 256), 256, 0, stream>>>(
            tW3, wt + 22L * WMAT, 11 * WMAT);
        transpose_conv<<<tg1, 256, 0, stream>>>(eW1, wt + 33L * WMAT);
        transpose_conv<<<tg1, 256, 0, stream>>>(eW2, wt + 34L * WMAT);
        transpose_conv<<<tg1, 256, 0, stream>>>(eW3, wt + 35L * WMAT);

        hipMemsetAsync(zero512, 0, 512 * sizeof(float), stream);
        // Mt_k^T = eW1^T @ tW3_k^T  (C[n][i] = sum_d eW1[d][n]*tW3[i][d])
        gemm_bt<false><<<dim3(4, 1, 11), 512, 0, stream>>>(
            wt + 33L * WMAT, 0, wt + 22L * WMAT, WMAT, zero512, 0, Mt + WMAT, WMAT);
        hipMemcpyAsync(Mt, wt + 33L * WMAT, WMAT * sizeof(short),
                       hipMemcpyDeviceToDevice, stream);
        hipMemcpyAsync(bB, eb1, 512 * sizeof(float),
                       hipMemcpyDeviceToDevice, stream);
        bias_fold<<<(11 * 512) / 4, 256, 0, stream>>>(tb3, wt + 33L * WMAT, eb1, bB);
    }

    const long SC = CH * 512;
    const dim3 gT((unsigned)(CH / 256 * 2), 1, 11);       // L1,L2: M = CH, per-k weights
    const dim3 gF((unsigned)(CH / 256 * 2), 1, 12);       // fold pass: 12 views
    const dim3 gE((unsigned)(12 * CH / 256 * 2), 1, 1);   // E2,E3: M = 12*CH

    for (int ch = 0; ch < c; ++ch) {
        // x chunk -> bf16 into S slot 0
        conv_f32_bf16<<<(unsigned)((SC / 4 + 255) / 256), 256, 0, stream>>>(
            x + (long)ch * SC, S, SC);

        // L1: h1 = gelu(x @ tW1_k + tb1_k)            -> T slots 1..11
        gemm_bt<true ><<<gT, 512, 0, stream>>>(S, 0,  wt + 0L * WMAT,  WMAT, tb1, 512, T + SC, SC);
        // L2: h2 = gelu(h1 @ tW2_k + tb2_k)           -> S slots 1..11
        gemm_bt<true ><<<gT, 512, 0, stream>>>(T + SC, SC, wt + 11L * WMAT, WMAT, tb2, 512, S + SC, SC);
        // F : E1out = gelu(S_z @ M_z + b_z)  (z=0: x,eW1,eb1) -> T slots 0..11
        gemm_bt<true ><<<gF, 512, 0, stream>>>(S, SC, Mt, WMAT, bB, 512, T, SC);
        // E2 -> S ; E3 -> T
        gemm_bt<true ><<<gE, 512, 0, stream>>>(T, 0, wt + 34L * WMAT, 0, eb2, 0, S, 0);
        gemm_bt<false><<<gE, 512, 0, stream>>>(S, 0, wt + 35L * WMAT, 0, eb3, 0, T, 0);

        // fused LN + L2-normalize + MFMA Gram + loss
        ln_loss<<<(unsigned)(CH / 4), 256, 0, stream>>>(
            T, ln_g, ln_b, (float*)d_out + (long)ch * CH, (int)CH);
    }
}